// Round 13
// baseline (1454.134 us; speedup 1.0000x reference)
//
#include <hip/hip_runtime.h>
#include <hip/hip_bf16.h>
#include <stdint.h>

#define NN 200000
#define MM 100000
#define EE 600000
#define BB 64
#define F_IN 256
#define HH 256
#define EMB 128
#define VV 512
#define NSRT 5

typedef __attribute__((ext_vector_type(8))) short bf16x8;
typedef __attribute__((ext_vector_type(4))) float f32x4;

__device__ __forceinline__ unsigned short f2bf(float x){
    union { float f; unsigned int u; } c; c.f = x;
    unsigned int r = c.u + 0x7FFFu + ((c.u >> 16) & 1u);
    return (unsigned short)(r >> 16);
}
__device__ __forceinline__ float bf2f(unsigned short b){
    union { unsigned int u; float f; } c; c.u = ((unsigned int)b) << 16;
    return c.f;
}

__device__ __forceinline__ int lowerb(const int* a, int n, int key){
    int lo = 0, hi = n;
    while (lo < hi){ int mid = (lo + hi) >> 1; if (a[mid] < key) lo = mid + 1; else hi = mid; }
    return lo;
}

#define GLDS16(g, l) __builtin_amdgcn_global_load_lds( \
    (const __attribute__((address_space(1))) unsigned int*)(g), \
    (__attribute__((address_space(3))) unsigned int*)(l), 16, 0, 0)

// ---- per-graph mean of x ----
#define CTX_RPB 128
__global__ __launch_bounds__(256) void ctxsum_kernel(const float* __restrict__ x,
        const int* __restrict__ xb, float* __restrict__ sum){
    int r0 = blockIdx.x * CTX_RPB;
    int r1 = r0 + CTX_RPB; if (r1 > MM) r1 = MM;
    int t = threadIdx.x;
    float s = 0.f;
    int g = xb[r0];
    for (int r = r0; r < r1; ++r){
        int gb = xb[r];
        if (gb != g){ atomicAdd(&sum[g * F_IN + t], s); s = 0.f; g = gb; }
        s += x[(size_t)r * F_IN + t];
    }
    atomicAdd(&sum[g * F_IN + t], s);
}

__global__ __launch_bounds__(256) void ctxdiv_kernel(const float* __restrict__ sum,
        const int* __restrict__ xb, float* __restrict__ ctx){
    int g = blockIdx.x, t = threadIdx.x;
    int lo = lowerb(xb, MM, g), hi = lowerb(xb, MM, g + 1);
    int c = hi - lo; if (c < 1) c = 1;
    ctx[g * F_IN + t] = sum[g * F_IN + t] / (float)c;
}

__global__ __launch_bounds__(64) void ctxb_kernel(const float* __restrict__ ctx,
        const float* __restrict__ Wc, const float* __restrict__ b,
        float* __restrict__ out, int dout){
    int g = blockIdx.x; int j = blockIdx.y * 64 + threadIdx.x;
    float acc = b[j];
    const float* cr = ctx + g * F_IN;
    for (int k = 0; k < F_IN; ++k) acc += cr[k] * Wc[(size_t)k * dout + j];
    out[(size_t)g * dout + j] = acc;
}

// WT[j][k] (K-stacked form)
__global__ __launch_bounds__(256) void build_wt(const float* __restrict__ Ws,
        const float* __restrict__ Wr, unsigned short* __restrict__ WT,
        int din, int dout, int ktot){
    size_t idx = (size_t)blockIdx.x * 256 + threadIdx.x;
    size_t total = (size_t)dout * ktot;
    if (idx >= total) return;
    int j = (int)(idx / ktot), k = (int)(idx % ktot);
    float v = (k < din) ? Ws[(size_t)k * dout + j] : Wr[(size_t)(k - din) * dout + j];
    WT[idx] = f2bf(v);
}

// WTp[jj][k] (N-stacked form)
__global__ __launch_bounds__(256) void build_wtp(const float* __restrict__ Ws,
        const float* __restrict__ Wr, unsigned short* __restrict__ WT,
        int K, int dout){
    size_t idx = (size_t)blockIdx.x * 256 + threadIdx.x;
    size_t total = (size_t)5 * dout * K;
    if (idx >= total) return;
    int jj = (int)(idx / K), k = (int)(idx % K);
    int blk = jj / dout, j = jj % dout;
    float v = (blk == 0) ? Ws[(size_t)k * dout + j]
                         : Wr[((size_t)(blk - 1) * K + k) * dout + j];
    WT[idx] = f2bf(v);
}

__global__ __launch_bounds__(256) void embed_kernel(const int* __restrict__ ty,
        const float* __restrict__ emb, unsigned short* __restrict__ h0){
    size_t idx = (size_t)blockIdx.x * 256 + threadIdx.x;
    int i = (int)(idx >> 7), c = (int)(idx & 127);
    int t0 = ty[i * 3], t1 = ty[i * 3 + 1], t2 = ty[i * 3 + 2];
    float v = emb[(size_t)t0 * EMB + c] + emb[(size_t)t1 * EMB + c] + emb[(size_t)t2 * EMB + c];
    h0[idx] = f2bf(v);
}

__global__ __launch_bounds__(256) void hist_kernel(const int* __restrict__ dst, int* __restrict__ deg){
    int e = blockIdx.x * 256 + threadIdx.x; if (e >= EE) return;
    atomicAdd(&deg[dst[e]], 1);
}

#define SNB ((NN + 1023) / 1024)

__global__ __launch_bounds__(256) void scanA_kernel(const int* __restrict__ deg,
        int* __restrict__ bsum){
    __shared__ int wsum[4];
    int tid = threadIdx.x, wid = tid >> 6, lane = tid & 63;
    int base = blockIdx.x * 1024 + tid * 4;
    int s = 0;
    if (base + 3 < NN){ int4 v = *(const int4*)(deg + base); s = v.x + v.y + v.z + v.w; }
    else { for (int i = 0; i < 4; ++i){ int idx = base + i; if (idx < NN) s += deg[idx]; } }
#pragma unroll
    for (int off = 1; off < 64; off <<= 1) s += __shfl_xor(s, off);
    if (lane == 0) wsum[wid] = s;
    __syncthreads();
    if (tid == 0) bsum[blockIdx.x] = wsum[0] + wsum[1] + wsum[2] + wsum[3];
}

__global__ __launch_bounds__(256) void scanB_kernel(const int* __restrict__ bsum,
        int* __restrict__ boff){
    __shared__ int lds[256];
    int t = threadIdx.x;
    int v = (t < SNB) ? bsum[t] : 0;
    lds[t] = v; __syncthreads();
    for (int off = 1; off < 256; off <<= 1){
        int n = (t >= off) ? lds[t - off] : 0;
        __syncthreads();
        lds[t] += n;
        __syncthreads();
    }
    if (t < SNB) boff[t] = lds[t] - v;
}

__global__ __launch_bounds__(256) void scanC_kernel(const int* __restrict__ deg,
        const int* __restrict__ boff, int* __restrict__ rowptr, int* __restrict__ cursor){
    __shared__ int wsum[4];
    int tid = threadIdx.x, wid = tid >> 6, lane = tid & 63;
    int base = blockIdx.x * 1024 + tid * 4;
    int d0 = 0, d1 = 0, d2 = 0, d3 = 0;
    if (base + 3 < NN){ int4 v = *(const int4*)(deg + base); d0 = v.x; d1 = v.y; d2 = v.z; d3 = v.w; }
    else if (base < NN){
        d0 = deg[base];
        if (base + 1 < NN) d1 = deg[base + 1];
        if (base + 2 < NN) d2 = deg[base + 2];
    }
    int tsum = d0 + d1 + d2 + d3;
    int run = tsum;
#pragma unroll
    for (int off = 1; off < 64; off <<= 1){
        int n = __shfl_up(run, off);
        if (lane >= off) run += n;
    }
    if (lane == 63) wsum[wid] = run;
    int texcl = run - tsum;
    __syncthreads();
    int woff = 0;
    for (int i = 0; i < wid; ++i) woff += wsum[i];
    int p = boff[blockIdx.x] + woff + texcl;
    if (base < NN){
        rowptr[base] = p; cursor[base] = p; p += d0;
        if (base + 1 < NN){ rowptr[base + 1] = p; cursor[base + 1] = p; p += d1; }
        if (base + 2 < NN){ rowptr[base + 2] = p; cursor[base + 2] = p; p += d2; }
        if (base + 3 < NN){ rowptr[base + 3] = p; cursor[base + 3] = p; p += d3; }
    }
    if (blockIdx.x == 0 && tid == 0) rowptr[NN] = EE;
}

__global__ __launch_bounds__(256) void fill_kernel(const int* __restrict__ src,
        const int* __restrict__ dst, const int* __restrict__ et,
        int* __restrict__ cursor, int* __restrict__ eidx){
    int e = blockIdx.x * 256 + threadIdx.x; if (e >= EE) return;
    int p = atomicAdd(&cursor[dst[e]], 1);
    eidx[p] = src[e] | (et[e] << 28);
}

// S[d][r][:] = sum of h[src] over incoming edges of type r
template<int DIN>
__global__ __launch_bounds__(256) void sbuild_kernel(const unsigned short* __restrict__ h,
        const int* __restrict__ rowptr, const int* __restrict__ eidx,
        unsigned short* __restrict__ S){
    constexpr int CPL = DIN / 64;
    int wid = threadIdx.x >> 6, lane = threadIdx.x & 63;
    int d = blockIdx.x * 4 + wid;
    int lo = rowptr[d], hi = rowptr[d + 1];
    float acc0[CPL], acc1[CPL], acc2[CPL], acc3[CPL];
#pragma unroll
    for (int c = 0; c < CPL; ++c){ acc0[c] = 0.f; acc1[c] = 0.f; acc2[c] = 0.f; acc3[c] = 0.f; }
    const unsigned short* hl = h + lane * CPL;
    int e = lo;
    for (; e + 1 < hi; e += 2){
        int pkA = eidx[e], pkB = eidx[e + 1];
        int sA = pkA & 0x0FFFFFFF, rA = pkA >> 28;
        int sB = pkB & 0x0FFFFFFF, rB = pkB >> 28;
        unsigned short vA[CPL], vB[CPL];
        if (CPL == 4){
            *(uint2*)vA = *(const uint2*)(hl + (size_t)sA * DIN);
            *(uint2*)vB = *(const uint2*)(hl + (size_t)sB * DIN);
        } else {
            *(unsigned int*)vA = *(const unsigned int*)(hl + (size_t)sA * DIN);
            *(unsigned int*)vB = *(const unsigned int*)(hl + (size_t)sB * DIN);
        }
        float a0 = (rA == 0) ? 1.f : 0.f, a1 = (rA == 1) ? 1.f : 0.f;
        float a2 = (rA == 2) ? 1.f : 0.f, a3 = (rA == 3) ? 1.f : 0.f;
        float b0 = (rB == 0) ? 1.f : 0.f, b1 = (rB == 1) ? 1.f : 0.f;
        float b2 = (rB == 2) ? 1.f : 0.f, b3 = (rB == 3) ? 1.f : 0.f;
#pragma unroll
        for (int c = 0; c < CPL; ++c){
            float fA = bf2f(vA[c]), fB = bf2f(vB[c]);
            acc0[c] += a0 * fA + b0 * fB;
            acc1[c] += a1 * fA + b1 * fB;
            acc2[c] += a2 * fA + b2 * fB;
            acc3[c] += a3 * fA + b3 * fB;
        }
    }
    if (e < hi){
        int pk = eidx[e];
        int s = pk & 0x0FFFFFFF, r = pk >> 28;
        unsigned short v[CPL];
        if (CPL == 4) *(uint2*)v = *(const uint2*)(hl + (size_t)s * DIN);
        else          *(unsigned int*)v = *(const unsigned int*)(hl + (size_t)s * DIN);
        float m0 = (r == 0) ? 1.f : 0.f, m1 = (r == 1) ? 1.f : 0.f;
        float m2 = (r == 2) ? 1.f : 0.f, m3 = (r == 3) ? 1.f : 0.f;
#pragma unroll
        for (int c = 0; c < CPL; ++c){
            float f = bf2f(v[c]);
            acc0[c] += m0 * f; acc1[c] += m1 * f; acc2[c] += m2 * f; acc3[c] += m3 * f;
        }
    }
    unsigned short* So = S + (size_t)d * 4 * DIN + lane * CPL;
    unsigned short o[CPL];
#pragma unroll
    for (int c = 0; c < CPL; ++c) o[c] = f2bf(acc0[c]);
    if (CPL == 4) *(uint2*)(So) = *(uint2*)o; else *(unsigned int*)(So) = *(unsigned int*)o;
#pragma unroll
    for (int c = 0; c < CPL; ++c) o[c] = f2bf(acc1[c]);
    if (CPL == 4) *(uint2*)(So + DIN) = *(uint2*)o; else *(unsigned int*)(So + DIN) = *(unsigned int*)o;
#pragma unroll
    for (int c = 0; c < CPL; ++c) o[c] = f2bf(acc2[c]);
    if (CPL == 4) *(uint2*)(So + 2 * DIN) = *(uint2*)o; else *(unsigned int*)(So + 2 * DIN) = *(unsigned int*)o;
#pragma unroll
    for (int c = 0; c < CPL; ++c) o[c] = f2bf(acc3[c]);
    if (CPL == 4) *(uint2*)(So + 3 * DIN) = *(uint2*)o; else *(unsigned int*)(So + 3 * DIN) = *(unsigned int*)o;
}

// out[d] = relu(G[d][self] + sum_{e->d} G[src_e][(1+r)*DOUT] + ctxb[yb[d]])
template<int DOUT, bool OUTF>
__global__ __launch_bounds__(256) void agg_kernel(const unsigned short* __restrict__ G,
        const int* __restrict__ rowptr, const int* __restrict__ eidx,
        const float* __restrict__ ctxb, const int* __restrict__ yb,
        unsigned short* __restrict__ hout, float* __restrict__ fout){
    constexpr int CPL = DOUT / 64;
    constexpr int STR = 5 * DOUT;
    int wid = threadIdx.x >> 6, lane = threadIdx.x & 63;
    int d = blockIdx.x * 4 + wid;
    int lo = rowptr[d], hi = rowptr[d + 1];
    int g = yb[d];
    const unsigned short* Gl = G + lane * CPL;
    float acc[CPL];
    {
        unsigned short sv[CPL];
        if (CPL == 4) *(uint2*)sv = *(const uint2*)(Gl + (size_t)d * STR);
        else          *(unsigned int*)sv = *(const unsigned int*)(Gl + (size_t)d * STR);
#pragma unroll
        for (int c = 0; c < CPL; ++c) acc[c] = bf2f(sv[c]);
    }
    int e = lo;
    for (; e + 1 < hi; e += 2){
        int pkA = eidx[e], pkB = eidx[e + 1];
        int sA = pkA & 0x0FFFFFFF, rA = pkA >> 28;
        int sB = pkB & 0x0FFFFFFF, rB = pkB >> 28;
        const unsigned short* ga = Gl + (size_t)sA * STR + (1 + rA) * DOUT;
        const unsigned short* gb = Gl + (size_t)sB * STR + (1 + rB) * DOUT;
        unsigned short vA[CPL], vB[CPL];
        if (CPL == 4){ *(uint2*)vA = *(const uint2*)ga; *(uint2*)vB = *(const uint2*)gb; }
        else { *(unsigned int*)vA = *(const unsigned int*)ga; *(unsigned int*)vB = *(const unsigned int*)gb; }
#pragma unroll
        for (int c = 0; c < CPL; ++c) acc[c] += bf2f(vA[c]) + bf2f(vB[c]);
    }
    if (e < hi){
        int pk = eidx[e];
        int s = pk & 0x0FFFFFFF, r = pk >> 28;
        const unsigned short* ga = Gl + (size_t)s * STR + (1 + r) * DOUT;
        unsigned short v[CPL];
        if (CPL == 4) *(uint2*)v = *(const uint2*)ga;
        else          *(unsigned int*)v = *(const unsigned int*)ga;
#pragma unroll
        for (int c = 0; c < CPL; ++c) acc[c] += bf2f(v[c]);
    }
    const float* cb = ctxb + (size_t)g * DOUT + lane * CPL;
    float f[CPL];
    unsigned short o[CPL];
#pragma unroll
    for (int c = 0; c < CPL; ++c){ f[c] = fmaxf(acc[c] + cb[c], 0.f); o[c] = f2bf(f[c]); }
    unsigned short* ho = hout + (size_t)d * DOUT + lane * CPL;
    if (CPL == 4) *(uint2*)ho = *(uint2*)o; else *(unsigned int*)ho = *(unsigned int*)o;
    if (OUTF){
        float* fo = fout + (size_t)d * DOUT + lane * CPL;
        if (CPL == 4){ float4 q = {f[0], f[1], f[2], f[3]}; *(float4*)fo = q; }
        else { float2 q = {f[0], f[1]}; *(float2*)fo = q; }
    }
}

// 128x256-tile LDS-staged bf16 MFMA GEMM, BK=64, double-buffered, 8 waves (2M x 4N,
// per-wave 64x64 = 4x4 frags, 32 MFMA/K-step). 96 KB LDS -> 1 block/CU. Coalesced
// epilogue through 64 KB LDS C-tile (reuses B buffers), 512B contiguous row stores.
template<int KTOT, int DIN, int NYT, bool HAS_S, bool RELUCTX>
__global__ __launch_bounds__(512, 2) void gemm256(
        const unsigned short* __restrict__ hA,
        const unsigned short* __restrict__ S,
        const unsigned short* __restrict__ WT,
        const float* __restrict__ ctxb,
        const int* __restrict__ yb,
        unsigned short* __restrict__ outb,
        int outstride, int ctxstride){
    __shared__ unsigned short ldsA[2][128 * 64];   // 32 KB
    __shared__ unsigned short ldsB[2][256 * 64];   // 64 KB
    constexpr int NT = KTOT / 64;
    int tid = threadIdx.x;
    int wid = tid >> 6, lane = tid & 63;
    int l15 = lane & 15, lk = lane >> 4;
    int wr = wid >> 2, wc = wid & 3;

    int nwg = gridDim.x;
    int orig = blockIdx.x;
    int q = nwg >> 3, r8 = nwg & 7;
    int xcd = orig & 7, pos = orig >> 3;
    int wg = (xcd < r8 ? xcd * (q + 1) : r8 * (q + 1) + (xcd - r8) * q) + pos;
    int mrow0 = (wg / NYT) * 128;
    int ncol0 = (wg % NYT) * 256;

    f32x4 acc[4][4];
#pragma unroll
    for (int m = 0; m < 4; ++m)
#pragma unroll
        for (int n = 0; n < 4; ++n) acc[m][n] = (f32x4){0.f, 0.f, 0.f, 0.f};

    auto stage = [&](int kt, int buf){
#pragma unroll
        for (int i = 0; i < 2; ++i){               // A: 128 rows x 8 chunks
            int idx = i * 512 + tid;
            int r = idx >> 3;
            int cbl = idx & 7;
            int cb = cbl ^ (r & 7);
            int k0 = kt * 64 + cb * 8;
            int gr = mrow0 + r; if (gr > NN - 1) gr = NN - 1;
            const unsigned short* ga;
            if (HAS_S && kt >= DIN / 64) ga = S + (size_t)gr * (4 * DIN) + (k0 - DIN);
            else                         ga = hA + (size_t)gr * DIN + k0;
            GLDS16(ga, &ldsA[buf][(size_t)(i * 8 + wid) * 512]);
        }
#pragma unroll
        for (int i = 0; i < 4; ++i){               // B: 256 rows x 8 chunks
            int idx = i * 512 + tid;
            int r = idx >> 3;
            int cbl = idx & 7;
            int cb = cbl ^ (r & 7);
            int k0 = kt * 64 + cb * 8;
            const unsigned short* gb = WT + (size_t)(ncol0 + r) * KTOT + k0;
            GLDS16(gb, &ldsB[buf][(size_t)(i * 8 + wid) * 512]);
        }
    };

    stage(0, 0);
    __syncthreads();
    int buf = 0;
#pragma unroll 1
    for (int kt = 0; kt < NT; ++kt){
        if (kt + 1 < NT) stage(kt + 1, buf ^ 1);
#pragma unroll
        for (int ks = 0; ks < 2; ++ks){
            int c = ks * 4 + lk;
            bf16x8 a[4], b[4];
#pragma unroll
            for (int m = 0; m < 4; ++m){
                int r = wr * 64 + m * 16 + l15;
                a[m] = *(const bf16x8*)&ldsA[buf][r * 64 + (c ^ (r & 7)) * 8];
            }
#pragma unroll
            for (int n = 0; n < 4; ++n){
                int j = wc * 64 + n * 16 + l15;
                b[n] = *(const bf16x8*)&ldsB[buf][j * 64 + (c ^ (j & 7)) * 8];
            }
#pragma unroll
            for (int m = 0; m < 4; ++m)
#pragma unroll
                for (int n = 0; n < 4; ++n)
                    acc[m][n] = __builtin_amdgcn_mfma_f32_16x16x32_bf16(b[n], a[m], acc[m][n], 0, 0, 0);
        }
        __syncthreads();
        buf ^= 1;
    }

    // epilogue: fragments -> swizzled 64KB LDS C-tile (in ldsB) -> 512B row stores
    unsigned short* ldsC = &ldsB[0][0];            // 128 rows x 256 elems
#pragma unroll
    for (int m = 0; m < 4; ++m){
        int rl = wr * 64 + m * 16 + l15;
        int row = mrow0 + rl;
        const float* cb = RELUCTX ? (ctxb + (size_t)yb[row < NN ? row : NN - 1] * ctxstride) : ctxb;
#pragma unroll
        for (int n = 0; n < 4; ++n){
            int g = wc * 16 + n * 4 + lk;          // granule 0..63
            int gs = g ^ ((rl & 7) << 2);
            unsigned short o[4];
#pragma unroll
            for (int r = 0; r < 4; ++r){
                float v = acc[m][n][r] + cb[ncol0 + g * 4 + r];
                if (RELUCTX) v = fmaxf(v, 0.f);
                o[r] = f2bf(v);
            }
            *(uint2*)&ldsC[rl * 256 + gs * 4] = *(uint2*)o;
        }
    }
    __syncthreads();
#pragma unroll
    for (int i = 0; i < 8; ++i){
        int idx = i * 512 + tid;                   // 128 rows x 32 chunks(8 elems)
        int rl = idx >> 5;
        int c = idx & 31;
        int g0 = (2 * c) ^ ((rl & 7) << 2);        // even granule, 16B-aligned
        bf16x8 v = *(const bf16x8*)&ldsC[rl * 256 + g0 * 4];
        int row = mrow0 + rl;
        if (row < NN)
            *(bf16x8*)(outb + (size_t)row * outstride + ncol0 + c * 8) = v;
    }
}

// 128x128-tile GEMM (kept for G3: 640-wide output), coalesced C-tile epilogue.
template<int KTOT, int DIN, int NYT, bool HAS_S, bool RELUCTX>
__global__ __launch_bounds__(512, 4) void gemm128(
        const unsigned short* __restrict__ hA,
        const unsigned short* __restrict__ S,
        const unsigned short* __restrict__ WT,
        const float* __restrict__ ctxb,
        const int* __restrict__ yb,
        unsigned short* __restrict__ outb,
        int outstride, int ctxstride){
    __shared__ unsigned short lds[2][2][128 * 64];
    constexpr int NT = KTOT / 64;
    int tid = threadIdx.x;
    int wid = tid >> 6, lane = tid & 63;
    int l15 = lane & 15, lk = lane >> 4;
    int wr = wid >> 2, wc = wid & 3;

    int nwg = gridDim.x;
    int orig = blockIdx.x;
    int q = nwg >> 3, r8 = nwg & 7;
    int xcd = orig & 7, pos = orig >> 3;
    int wg = (xcd < r8 ? xcd * (q + 1) : r8 * (q + 1) + (xcd - r8) * q) + pos;
    int mrow0 = (wg / NYT) * 128;
    int ncol0 = (wg % NYT) * 128;

    f32x4 acc[4][2];
#pragma unroll
    for (int m = 0; m < 4; ++m)
#pragma unroll
        for (int n = 0; n < 2; ++n) acc[m][n] = (f32x4){0.f, 0.f, 0.f, 0.f};

    auto stage = [&](int kt, int buf){
#pragma unroll
        for (int i = 0; i < 2; ++i){
            int idx = i * 512 + tid;
            int r = idx >> 3;
            int cbl = idx & 7;
            int cb = cbl ^ (r & 7);
            int k0 = kt * 64 + cb * 8;
            int gr = mrow0 + r; if (gr > NN - 1) gr = NN - 1;
            const unsigned short* ga;
            if (HAS_S && kt >= DIN / 64) ga = S + (size_t)gr * (4 * DIN) + (k0 - DIN);
            else                         ga = hA + (size_t)gr * DIN + k0;
            GLDS16(ga, &lds[buf][0][(size_t)(i * 8 + wid) * 512]);
            int gj = ncol0 + r;
            const unsigned short* gb = WT + (size_t)gj * KTOT + k0;
            GLDS16(gb, &lds[buf][1][(size_t)(i * 8 + wid) * 512]);
        }
    };

    stage(0, 0);
    __syncthreads();
    int buf = 0;
#pragma unroll 1
    for (int kt = 0; kt < NT; ++kt){
        if (kt + 1 < NT) stage(kt + 1, buf ^ 1);
#pragma unroll
        for (int ks = 0; ks < 2; ++ks){
            int c = ks * 4 + lk;
            bf16x8 a[4], b[2];
#pragma unroll
            for (int m = 0; m < 4; ++m){
                int r = wr * 64 + m * 16 + l15;
                a[m] = *(const bf16x8*)&lds[buf][0][r * 64 + (c ^ (r & 7)) * 8];
            }
#pragma unroll
            for (int n = 0; n < 2; ++n){
                int j = wc * 32 + n * 16 + l15;
                b[n] = *(const bf16x8*)&lds[buf][1][j * 64 + (c ^ (j & 7)) * 8];
            }
#pragma unroll
            for (int m = 0; m < 4; ++m)
#pragma unroll
                for (int n = 0; n < 2; ++n)
                    acc[m][n] = __builtin_amdgcn_mfma_f32_16x16x32_bf16(b[n], a[m], acc[m][n], 0, 0, 0);
        }
        __syncthreads();
        buf ^= 1;
    }

    unsigned short* ldsC = &lds[0][0][0];
#pragma unroll
    for (int m = 0; m < 4; ++m){
        int rl = wr * 64 + m * 16 + l15;
        int row = mrow0 + rl;
        const float* cb = RELUCTX ? (ctxb + (size_t)yb[row < NN ? row : NN - 1] * ctxstride) : ctxb;
#pragma unroll
        for (int n = 0; n < 2; ++n){
            int g = wc * 8 + n * 4 + lk;
            int gs = g ^ ((rl & 7) << 2);
            unsigned short o[4];
#pragma unroll
            for (int r = 0; r < 4; ++r){
                float v = acc[m][n][r] + cb[ncol0 + g * 4 + r];
                if (RELUCTX) v = fmaxf(v, 0.f);
                o[r] = f2bf(v);
            }
            *(uint2*)&ldsC[rl * 128 + gs * 4] = *(uint2*)o;
        }
    }
    __syncthreads();
#pragma unroll
    for (int i = 0; i < 4; ++i){
        int idx = i * 512 + tid;
        int rl = idx >> 4;
        int c = idx & 15;
        int g0 = (2 * c) ^ ((rl & 7) << 2);
        bf16x8 v = *(const bf16x8*)&ldsC[rl * 128 + g0 * 4];
        int row = mrow0 + rl;
        if (row < NN)
            *(bf16x8*)(outb + (size_t)row * outstride + ncol0 + c * 8) = v;
    }
}

// Fused y_pred = log_softmax(ybf @ WTz^T + lzb)
__global__ __launch_bounds__(512, 2) void logit_lsm_kernel(
        const unsigned short* __restrict__ ybf,
        const unsigned short* __restrict__ WTz,
        const float* __restrict__ lzb,
        float* __restrict__ ypred){
    __shared__ unsigned short ldsB[2][VV * 32];
    __shared__ float lzbs[VV];
    __shared__ float pm[4][16][2], ps[4][16][2];
    int tid = threadIdx.x;
    int wid = tid >> 6, lane = tid & 63;
    int l15 = lane & 15, lk = lane >> 4;
    int wr = wid >> 1, wc = wid & 1;
    int row = blockIdx.x * 64 + wr * 16 + l15;

    lzbs[tid] = lzb[tid];

    bf16x8 aR[4];
    const unsigned short* ap = ybf + (size_t)row * EMB;
#pragma unroll
    for (int kt = 0; kt < 4; ++kt) aR[kt] = *(const bf16x8*)(ap + kt * 32 + lk * 8);

    auto stageB = [&](int kt, int buf){
#pragma unroll
        for (int i = 0; i < 4; ++i){
            int idx = i * 512 + tid;
            int j = idx >> 2;
            int cbl = idx & 3;
            int cb = cbl ^ (j & 3);
            const unsigned short* gb = WTz + (size_t)j * EMB + kt * 32 + cb * 8;
            GLDS16(gb, &ldsB[buf][(size_t)(i * 8 + wid) * 512]);
        }
    };

    f32x4 acc[16];
#pragma unroll
    for (int n = 0; n < 16; ++n) acc[n] = (f32x4){0.f, 0.f, 0.f, 0.f};

    stageB(0, 0);
    __syncthreads();
    int buf = 0;
#pragma unroll
    for (int kt = 0; kt < 4; ++kt){
        if (kt < 3) stageB(kt + 1, buf ^ 1);
#pragma unroll
        for (int nh = 0; nh < 2; ++nh){
            bf16x8 b[8];
#pragma unroll
            for (int n8 = 0; n8 < 8; ++n8){
                int j = wc * 256 + (nh * 8 + n8) * 16 + l15;
                b[n8] = *(const bf16x8*)&ldsB[buf][j * 32 + ((lk ^ (j & 3)) * 8)];
            }
#pragma unroll
            for (int n8 = 0; n8 < 8; ++n8)
                acc[nh * 8 + n8] = __builtin_amdgcn_mfma_f32_16x16x32_bf16(b[n8], aR[kt], acc[nh * 8 + n8], 0, 0, 0);
        }
        __syncthreads();
        buf ^= 1;
    }

    float m = -3.0e38f;
#pragma unroll
    for (int n = 0; n < 16; ++n){
        int colb = wc * 256 + n * 16 + lk * 4;
#pragma unroll
        for (int r = 0; r < 4; ++r){
            float v = acc[n][r] + lzbs[colb + r];
            acc[n][r] = v;
            m = fmaxf(m, v);
        }
    }
    m = fmaxf(m, __shfl_xor(m, 16));
    m = fmaxf(m, __shfl_xor(m, 32));
    float s = 0.f;
#pragma unroll
    for (int n = 0; n < 16; ++n)
#pragma unroll
        for (int r = 0; r < 4; ++r) s += expf(acc[n][r] - m);
    s += __shfl_xor(s, 16);
    s += __shfl_xor(s, 32);
    if (lk == 0){ pm[wr][l15][wc] = m; ps[wr][l15][wc] = s; }
    __syncthreads();
    float m0 = pm[wr][l15][0], m1 = pm[wr][l15][1];
    float s0 = ps[wr][l15][0], s1 = ps[wr][l15][1];
    float M = fmaxf(m0, m1);
    float l = M + logf(expf(m0 - M) * s0 + expf(m1 - M) * s1);

    float* orow = ypred + (size_t)row * VV + wc * 256;
#pragma unroll
    for (int n = 0; n < 16; ++n){
        int colb = n * 16 + lk * 4;
        float4 q = {acc[n][0] - l, acc[n][1] - l, acc[n][2] - l, acc[n][3] - l};
        *(float4*)(orow + colb) = q;
    }
}

// ---- edge head, factored ----
__global__ __launch_bounds__(256) void zpair_kernel(const float* __restrict__ y,
        const float* __restrict__ Wg, float* __restrict__ z){
    __shared__ float ylds[16][132];
    __shared__ float wg[2 * EMB * NSRT];
    for (int i = threadIdx.x; i < 2 * EMB * NSRT; i += 256) wg[i] = Wg[i];
    int n0 = blockIdx.x * 16;
    for (int i = threadIdx.x; i < 16 * 32; i += 256){
        int node = i >> 5, f4 = i & 31;
        *(float4*)&ylds[node][f4 * 4] = *(const float4*)(y + (size_t)(n0 + node) * EMB + f4 * 4);
    }
    __syncthreads();
    int t = threadIdx.x;
    if (t < 160){
        int node = t & 15, c = t >> 4;
        int base = (c >= 5) ? EMB : 0;
        int cc = (c >= 5) ? c - 5 : c;
        float acc = 0.f;
#pragma unroll 4
        for (int k = 0; k < EMB; ++k) acc += ylds[node][k] * wg[(base + k) * NSRT + cc];
        z[(size_t)(n0 + node) * 10 + c] = acc;
    }
}

__global__ __launch_bounds__(256) void edge2_kernel(const int* __restrict__ src,
        const int* __restrict__ dst, const float* __restrict__ z,
        const float* __restrict__ bg, float* __restrict__ out){
    int e = blockIdx.x * 256 + threadIdx.x; if (e >= EE) return;
    int s = src[e], d = dst[e];
    const float* zs = z + (size_t)s * 10;
    const float* zd = z + (size_t)d * 10 + 5;
    float l0 = zs[0] + zd[0] + bg[0];
    float l1 = zs[1] + zd[1] + bg[1];
    float l2 = zs[2] + zd[2] + bg[2];
    float l3 = zs[3] + zd[3] + bg[3];
    float l4 = zs[4] + zd[4] + bg[4];
    float m = fmaxf(fmaxf(fmaxf(l0, l1), fmaxf(l2, l3)), l4);
    float ssum = expf(l0 - m) + expf(l1 - m) + expf(l2 - m) + expf(l3 - m) + expf(l4 - m);
    float lg = m + logf(ssum);
    float* o = out + (size_t)e * NSRT;
    o[0] = l0 - lg; o[1] = l1 - lg; o[2] = l2 - lg; o[3] = l3 - lg; o[4] = l4 - lg;
}

__global__ __launch_bounds__(256) void i2f_kernel(const int* __restrict__ in,
        float* __restrict__ out, int n){
    int i = blockIdx.x * 256 + threadIdx.x;
    if (i < n) out[i] = (float)in[i];
}

extern "C" void kernel_launch(void* const* d_in, const int* in_sizes, int n_in,
                              void* d_out, int out_size, void* d_ws, size_t ws_size,
                              hipStream_t stream){
    const float* x    = (const float*)d_in[0];
    const int*   xb   = (const int*)d_in[1];
    const int*   ty   = (const int*)d_in[2];
    const int*   ei   = (const int*)d_in[3];
    const int*   et   = (const int*)d_in[4];
    const int*   tyb  = (const int*)d_in[5];
    const float* emb  = (const float*)d_in[6];
    const float* Ws1 = (const float*)d_in[7],  *Wr1 = (const float*)d_in[8];
    const float* Wc1 = (const float*)d_in[9],  *b1  = (const float*)d_in[10];
    const float* Ws2 = (const float*)d_in[11], *Wr2 = (const float*)d_in[12];
    const float* Wc2 = (const float*)d_in[13], *b2  = (const float*)d_in[14];
    const float* Ws3 = (const float*)d_in[15], *Wr3 = (const float*)d_in[16];
    const float* Wc3 = (const float*)d_in[17], *b3  = (const float*)d_in[18];
    const float* lzw = (const float*)d_in[19], *lzb = (const float*)d_in[20];
    const float* lgw = (const float*)d_in[21], *lgb = (const float*)d_in[22];

    const int* src = ei;
    const int* dst = ei + EE;

    float* out = (float*)d_out;
    const size_t OFF_Y  = 0;
    const size_t OFF_EI = (size_t)NN * EMB;
    const size_t OFF_ET = OFF_EI + 2 * (size_t)EE;
    const size_t OFF_YP = OFF_ET + (size_t)EE;
    const size_t OFF_EP = OFF_YP + (size_t)NN * VV;

    char* w = (char*)d_ws;
    auto alloc = [&](size_t bytes){ char* p = w; w += (bytes + 255) & ~(size_t)255; return p; };
    unsigned short* h0  = (unsigned short*)alloc((size_t)NN * EMB * 2);
    unsigned short* h1  = (unsigned short*)alloc((size_t)NN * HH * 2);
    unsigned short* h2  = (unsigned short*)alloc((size_t)NN * HH * 2);
    unsigned short* ybf = (unsigned short*)alloc((size_t)NN * EMB * 2);
    unsigned short* G2  = (unsigned short*)alloc((size_t)NN * 5 * HH * 2);
    unsigned short* G3  = (unsigned short*)alloc((size_t)NN * 5 * EMB * 2);
    unsigned short* WT1 = (unsigned short*)alloc((size_t)HH * (5 * EMB) * 2);
    unsigned short* WT2p= (unsigned short*)alloc((size_t)(5 * HH) * HH * 2);
    unsigned short* WT3p= (unsigned short*)alloc((size_t)(5 * EMB) * HH * 2);
    unsigned short* WTz = (unsigned short*)alloc((size_t)VV * EMB * 2);
    float* ctxs  = (float*)alloc(BB * F_IN * 4);
    float* ctx   = (float*)alloc(BB * F_IN * 4);
    float* ctxb1 = (float*)alloc(BB * HH * 4);
    float* ctxb2 = (float*)alloc(BB * HH * 4);
    float* ctxb3 = (float*)alloc(BB * EMB * 4);
    float* zpair = (float*)alloc((size_t)NN * 10 * 4);
    float* zerob = (float*)alloc((size_t)5 * HH * 4);
    int* deg    = (int*)alloc((size_t)NN * 4);
    int* rowptr = (int*)alloc(((size_t)NN + 1) * 4);
    int* cursor = (int*)alloc((size_t)NN * 4);
    int* eidx   = (int*)alloc((size_t)EE * 4);
    int* bsum   = (int*)alloc((size_t)SNB * 4);
    int* boff   = (int*)alloc((size_t)SNB * 4);

    // y_pred region of d_out doubles as S scratch (layer 1 only) until logit_lsm
    unsigned short* Sbuf = (unsigned short*)(out + OFF_YP);

    // CSR by dst
    hipMemsetAsync(deg, 0, (size_t)NN * 4, stream);
    hipMemsetAsync(zerob, 0, (size_t)5 * HH * 4, stream);
    hist_kernel<<<(EE + 255) / 256, 256, 0, stream>>>(dst, deg);
    scanA_kernel<<<SNB, 256, 0, stream>>>(deg, bsum);
    scanB_kernel<<<1, 256, 0, stream>>>(bsum, boff);
    scanC_kernel<<<SNB, 256, 0, stream>>>(deg, boff, rowptr, cursor);
    fill_kernel<<<(EE + 255) / 256, 256, 0, stream>>>(src, dst, et, cursor, eidx);

    // ctx + folded ctx@Wc+b tables
    hipMemsetAsync(ctxs, 0, BB * F_IN * 4, stream);
    ctxsum_kernel<<<(MM + CTX_RPB - 1) / CTX_RPB, 256, 0, stream>>>(x, xb, ctxs);
    ctxdiv_kernel<<<BB, 256, 0, stream>>>(ctxs, xb, ctx);
    ctxb_kernel<<<dim3(BB, HH / 64), 64, 0, stream>>>(ctx, Wc1, b1, ctxb1, HH);
    ctxb_kernel<<<dim3(BB, HH / 64), 64, 0, stream>>>(ctx, Wc2, b2, ctxb2, HH);
    ctxb_kernel<<<dim3(BB, EMB / 64), 64, 0, stream>>>(ctx, Wc3, b3, ctxb3, EMB);

    // weight stacks
    build_wt<<<(HH * 5 * EMB + 255) / 256, 256, 0, stream>>>(Ws1, Wr1, WT1, EMB, HH, 5 * EMB);
    build_wtp<<<(5 * HH * HH + 255) / 256, 256, 0, stream>>>(Ws2, Wr2, WT2p, HH, HH);
    build_wtp<<<(5 * EMB * HH + 255) / 256, 256, 0, stream>>>(Ws3, Wr3, WT3p, HH, EMB);
    build_wt<<<(VV * EMB + 255) / 256, 256, 0, stream>>>(lzw, lzw, WTz, EMB, VV, EMB);

    // h0 = embeds[tgt_y].sum(1)
    embed_kernel<<<NN * EMB / 256, 256, 0, stream>>>(ty, emb, h0);

    const int MT = (NN + 127) / 128;  // 1563

    // layer 1: aggregate in din-space then fat GEMM (KTOT=640, BN=256)
    sbuild_kernel<EMB><<<NN / 4, 256, 0, stream>>>(h0, rowptr, eidx, Sbuf);
    gemm256<640, 128, 1, true, true><<<MT, 512, 0, stream>>>(
        h0, Sbuf, WT1, ctxb1, tyb, h1, HH, HH);

    // layer 2: project-first (BN=256, NYT=5) -> aggregate in dout-space
    gemm256<256, 256, 5, false, false><<<MT * 5, 512, 0, stream>>>(
        h1, nullptr, WT2p, zerob, nullptr, G2, 5 * HH, 0);
    agg_kernel<HH, false><<<NN / 4, 256, 0, stream>>>(
        G2, rowptr, eidx, ctxb2, tyb, h2, nullptr);

    // layer 3: project-first (BN=128, NYT=5) -> aggregate, dual f32+bf16 out
    gemm128<256, 256, 5, false, false><<<MT * 5, 512, 0, stream>>>(
        h2, nullptr, WT3p, zerob, nullptr, G3, 5 * EMB, 0);
    agg_kernel<EMB, true><<<NN / 4, 256, 0, stream>>>(
        G3, rowptr, eidx, ctxb3, tyb, ybf, out + OFF_Y);

    // edge head tables
    zpair_kernel<<<NN / 16, 256, 0, stream>>>(out + OFF_Y, lgw, zpair);

    // y_pred = log_softmax(y @ lin_z_w + lin_z_b), fused
    logit_lsm_kernel<<<NN / 64, 512, 0, stream>>>(ybf, WTz, lzb, out + OFF_YP);

    // per-edge head
    edge2_kernel<<<(EE + 255) / 256, 256, 0, stream>>>(src, dst, zpair, lgb, out + OFF_EP);
    i2f_kernel<<<(2 * EE + 255) / 256, 256, 0, stream>>>(ei, out + OFF_EI, 2 * EE);
    i2f_kernel<<<(EE + 255) / 256, 256, 0, stream>>>(et, out + OFF_ET, EE);
}

// Round 14
// 1387.302 us; speedup vs baseline: 1.0482x; 1.0482x over previous
//
#include <hip/hip_runtime.h>
#include <hip/hip_bf16.h>
#include <stdint.h>

#define NN 200000
#define MM 100000
#define EE 600000
#define BB 64
#define F_IN 256
#define HH 256
#define EMB 128
#define VV 512
#define NSRT 5

typedef __attribute__((ext_vector_type(8))) short bf16x8;
typedef __attribute__((ext_vector_type(4))) float f32x4;

__device__ __forceinline__ unsigned short f2bf(float x){
    union { float f; unsigned int u; } c; c.f = x;
    unsigned int r = c.u + 0x7FFFu + ((c.u >> 16) & 1u);
    return (unsigned short)(r >> 16);
}
__device__ __forceinline__ float bf2f(unsigned short b){
    union { unsigned int u; float f; } c; c.u = ((unsigned int)b) << 16;
    return c.f;
}

__device__ __forceinline__ int lowerb(const int* a, int n, int key){
    int lo = 0, hi = n;
    while (lo < hi){ int mid = (lo + hi) >> 1; if (a[mid] < key) lo = mid + 1; else hi = mid; }
    return lo;
}

#define GLDS16(g, l) __builtin_amdgcn_global_load_lds( \
    (const __attribute__((address_space(1))) unsigned int*)(g), \
    (__attribute__((address_space(3))) unsigned int*)(l), 16, 0, 0)

// ---- per-graph mean of x ----
#define CTX_RPB 128
__global__ __launch_bounds__(256) void ctxsum_kernel(const float* __restrict__ x,
        const int* __restrict__ xb, float* __restrict__ sum){
    int r0 = blockIdx.x * CTX_RPB;
    int r1 = r0 + CTX_RPB; if (r1 > MM) r1 = MM;
    int t = threadIdx.x;
    float s = 0.f;
    int g = xb[r0];
    for (int r = r0; r < r1; ++r){
        int gb = xb[r];
        if (gb != g){ atomicAdd(&sum[g * F_IN + t], s); s = 0.f; g = gb; }
        s += x[(size_t)r * F_IN + t];
    }
    atomicAdd(&sum[g * F_IN + t], s);
}

__global__ __launch_bounds__(256) void ctxdiv_kernel(const float* __restrict__ sum,
        const int* __restrict__ xb, float* __restrict__ ctx){
    int g = blockIdx.x, t = threadIdx.x;
    int lo = lowerb(xb, MM, g), hi = lowerb(xb, MM, g + 1);
    int c = hi - lo; if (c < 1) c = 1;
    ctx[g * F_IN + t] = sum[g * F_IN + t] / (float)c;
}

__global__ __launch_bounds__(64) void ctxb_kernel(const float* __restrict__ ctx,
        const float* __restrict__ Wc, const float* __restrict__ b,
        float* __restrict__ out, int dout){
    int g = blockIdx.x; int j = blockIdx.y * 64 + threadIdx.x;
    float acc = b[j];
    const float* cr = ctx + g * F_IN;
    for (int k = 0; k < F_IN; ++k) acc += cr[k] * Wc[(size_t)k * dout + j];
    out[(size_t)g * dout + j] = acc;
}

// WT[j][k] (K-stacked form)
__global__ __launch_bounds__(256) void build_wt(const float* __restrict__ Ws,
        const float* __restrict__ Wr, unsigned short* __restrict__ WT,
        int din, int dout, int ktot){
    size_t idx = (size_t)blockIdx.x * 256 + threadIdx.x;
    size_t total = (size_t)dout * ktot;
    if (idx >= total) return;
    int j = (int)(idx / ktot), k = (int)(idx % ktot);
    float v = (k < din) ? Ws[(size_t)k * dout + j] : Wr[(size_t)(k - din) * dout + j];
    WT[idx] = f2bf(v);
}

// WTp[jj][k] (N-stacked form)
__global__ __launch_bounds__(256) void build_wtp(const float* __restrict__ Ws,
        const float* __restrict__ Wr, unsigned short* __restrict__ WT,
        int K, int dout){
    size_t idx = (size_t)blockIdx.x * 256 + threadIdx.x;
    size_t total = (size_t)5 * dout * K;
    if (idx >= total) return;
    int jj = (int)(idx / K), k = (int)(idx % K);
    int blk = jj / dout, j = jj % dout;
    float v = (blk == 0) ? Ws[(size_t)k * dout + j]
                         : Wr[((size_t)(blk - 1) * K + k) * dout + j];
    WT[idx] = f2bf(v);
}

__global__ __launch_bounds__(256) void embed_kernel(const int* __restrict__ ty,
        const float* __restrict__ emb, unsigned short* __restrict__ h0){
    size_t idx = (size_t)blockIdx.x * 256 + threadIdx.x;
    int i = (int)(idx >> 7), c = (int)(idx & 127);
    int t0 = ty[i * 3], t1 = ty[i * 3 + 1], t2 = ty[i * 3 + 2];
    float v = emb[(size_t)t0 * EMB + c] + emb[(size_t)t1 * EMB + c] + emb[(size_t)t2 * EMB + c];
    h0[idx] = f2bf(v);
}

__global__ __launch_bounds__(256) void hist_kernel(const int* __restrict__ dst, int* __restrict__ deg){
    int e = blockIdx.x * 256 + threadIdx.x; if (e >= EE) return;
    atomicAdd(&deg[dst[e]], 1);
}

#define SNB ((NN + 1023) / 1024)

__global__ __launch_bounds__(256) void scanA_kernel(const int* __restrict__ deg,
        int* __restrict__ bsum){
    __shared__ int wsum[4];
    int tid = threadIdx.x, wid = tid >> 6, lane = tid & 63;
    int base = blockIdx.x * 1024 + tid * 4;
    int s = 0;
    if (base + 3 < NN){ int4 v = *(const int4*)(deg + base); s = v.x + v.y + v.z + v.w; }
    else { for (int i = 0; i < 4; ++i){ int idx = base + i; if (idx < NN) s += deg[idx]; } }
#pragma unroll
    for (int off = 1; off < 64; off <<= 1) s += __shfl_xor(s, off);
    if (lane == 0) wsum[wid] = s;
    __syncthreads();
    if (tid == 0) bsum[blockIdx.x] = wsum[0] + wsum[1] + wsum[2] + wsum[3];
}

__global__ __launch_bounds__(256) void scanB_kernel(const int* __restrict__ bsum,
        int* __restrict__ boff){
    __shared__ int lds[256];
    int t = threadIdx.x;
    int v = (t < SNB) ? bsum[t] : 0;
    lds[t] = v; __syncthreads();
    for (int off = 1; off < 256; off <<= 1){
        int n = (t >= off) ? lds[t - off] : 0;
        __syncthreads();
        lds[t] += n;
        __syncthreads();
    }
    if (t < SNB) boff[t] = lds[t] - v;
}

__global__ __launch_bounds__(256) void scanC_kernel(const int* __restrict__ deg,
        const int* __restrict__ boff, int* __restrict__ rowptr, int* __restrict__ cursor){
    __shared__ int wsum[4];
    int tid = threadIdx.x, wid = tid >> 6, lane = tid & 63;
    int base = blockIdx.x * 1024 + tid * 4;
    int d0 = 0, d1 = 0, d2 = 0, d3 = 0;
    if (base + 3 < NN){ int4 v = *(const int4*)(deg + base); d0 = v.x; d1 = v.y; d2 = v.z; d3 = v.w; }
    else if (base < NN){
        d0 = deg[base];
        if (base + 1 < NN) d1 = deg[base + 1];
        if (base + 2 < NN) d2 = deg[base + 2];
    }
    int tsum = d0 + d1 + d2 + d3;
    int run = tsum;
#pragma unroll
    for (int off = 1; off < 64; off <<= 1){
        int n = __shfl_up(run, off);
        if (lane >= off) run += n;
    }
    if (lane == 63) wsum[wid] = run;
    int texcl = run - tsum;
    __syncthreads();
    int woff = 0;
    for (int i = 0; i < wid; ++i) woff += wsum[i];
    int p = boff[blockIdx.x] + woff + texcl;
    if (base < NN){
        rowptr[base] = p; cursor[base] = p; p += d0;
        if (base + 1 < NN){ rowptr[base + 1] = p; cursor[base + 1] = p; p += d1; }
        if (base + 2 < NN){ rowptr[base + 2] = p; cursor[base + 2] = p; p += d2; }
        if (base + 3 < NN){ rowptr[base + 3] = p; cursor[base + 3] = p; p += d3; }
    }
    if (blockIdx.x == 0 && tid == 0) rowptr[NN] = EE;
}

__global__ __launch_bounds__(256) void fill_kernel(const int* __restrict__ src,
        const int* __restrict__ dst, const int* __restrict__ et,
        int* __restrict__ cursor, int* __restrict__ eidx){
    int e = blockIdx.x * 256 + threadIdx.x; if (e >= EE) return;
    int p = atomicAdd(&cursor[dst[e]], 1);
    eidx[p] = src[e] | (et[e] << 28);
}

// S[d][r][:] = sum of h[src] over incoming edges of type r
template<int DIN>
__global__ __launch_bounds__(256) void sbuild_kernel(const unsigned short* __restrict__ h,
        const int* __restrict__ rowptr, const int* __restrict__ eidx,
        unsigned short* __restrict__ S){
    constexpr int CPL = DIN / 64;
    int wid = threadIdx.x >> 6, lane = threadIdx.x & 63;
    int d = blockIdx.x * 4 + wid;
    int lo = rowptr[d], hi = rowptr[d + 1];
    float acc0[CPL], acc1[CPL], acc2[CPL], acc3[CPL];
#pragma unroll
    for (int c = 0; c < CPL; ++c){ acc0[c] = 0.f; acc1[c] = 0.f; acc2[c] = 0.f; acc3[c] = 0.f; }
    const unsigned short* hl = h + lane * CPL;
    int e = lo;
    for (; e + 1 < hi; e += 2){
        int pkA = eidx[e], pkB = eidx[e + 1];
        int sA = pkA & 0x0FFFFFFF, rA = pkA >> 28;
        int sB = pkB & 0x0FFFFFFF, rB = pkB >> 28;
        unsigned short vA[CPL], vB[CPL];
        if (CPL == 4){
            *(uint2*)vA = *(const uint2*)(hl + (size_t)sA * DIN);
            *(uint2*)vB = *(const uint2*)(hl + (size_t)sB * DIN);
        } else {
            *(unsigned int*)vA = *(const unsigned int*)(hl + (size_t)sA * DIN);
            *(unsigned int*)vB = *(const unsigned int*)(hl + (size_t)sB * DIN);
        }
        float a0 = (rA == 0) ? 1.f : 0.f, a1 = (rA == 1) ? 1.f : 0.f;
        float a2 = (rA == 2) ? 1.f : 0.f, a3 = (rA == 3) ? 1.f : 0.f;
        float b0 = (rB == 0) ? 1.f : 0.f, b1 = (rB == 1) ? 1.f : 0.f;
        float b2 = (rB == 2) ? 1.f : 0.f, b3 = (rB == 3) ? 1.f : 0.f;
#pragma unroll
        for (int c = 0; c < CPL; ++c){
            float fA = bf2f(vA[c]), fB = bf2f(vB[c]);
            acc0[c] += a0 * fA + b0 * fB;
            acc1[c] += a1 * fA + b1 * fB;
            acc2[c] += a2 * fA + b2 * fB;
            acc3[c] += a3 * fA + b3 * fB;
        }
    }
    if (e < hi){
        int pk = eidx[e];
        int s = pk & 0x0FFFFFFF, r = pk >> 28;
        unsigned short v[CPL];
        if (CPL == 4) *(uint2*)v = *(const uint2*)(hl + (size_t)s * DIN);
        else          *(unsigned int*)v = *(const unsigned int*)(hl + (size_t)s * DIN);
        float m0 = (r == 0) ? 1.f : 0.f, m1 = (r == 1) ? 1.f : 0.f;
        float m2 = (r == 2) ? 1.f : 0.f, m3 = (r == 3) ? 1.f : 0.f;
#pragma unroll
        for (int c = 0; c < CPL; ++c){
            float f = bf2f(v[c]);
            acc0[c] += m0 * f; acc1[c] += m1 * f; acc2[c] += m2 * f; acc3[c] += m3 * f;
        }
    }
    unsigned short* So = S + (size_t)d * 4 * DIN + lane * CPL;
    unsigned short o[CPL];
#pragma unroll
    for (int c = 0; c < CPL; ++c) o[c] = f2bf(acc0[c]);
    if (CPL == 4) *(uint2*)(So) = *(uint2*)o; else *(unsigned int*)(So) = *(unsigned int*)o;
#pragma unroll
    for (int c = 0; c < CPL; ++c) o[c] = f2bf(acc1[c]);
    if (CPL == 4) *(uint2*)(So + DIN) = *(uint2*)o; else *(unsigned int*)(So + DIN) = *(unsigned int*)o;
#pragma unroll
    for (int c = 0; c < CPL; ++c) o[c] = f2bf(acc2[c]);
    if (CPL == 4) *(uint2*)(So + 2 * DIN) = *(uint2*)o; else *(unsigned int*)(So + 2 * DIN) = *(unsigned int*)o;
#pragma unroll
    for (int c = 0; c < CPL; ++c) o[c] = f2bf(acc3[c]);
    if (CPL == 4) *(uint2*)(So + 3 * DIN) = *(uint2*)o; else *(unsigned int*)(So + 3 * DIN) = *(unsigned int*)o;
}

// out[d] = relu(G[d][self] + sum_{e->d} G[src_e][(1+r)*DOUT] + ctxb[yb[d]])
template<int DOUT, bool OUTF>
__global__ __launch_bounds__(256) void agg_kernel(const unsigned short* __restrict__ G,
        const int* __restrict__ rowptr, const int* __restrict__ eidx,
        const float* __restrict__ ctxb, const int* __restrict__ yb,
        unsigned short* __restrict__ hout, float* __restrict__ fout){
    constexpr int CPL = DOUT / 64;
    constexpr int STR = 5 * DOUT;
    int wid = threadIdx.x >> 6, lane = threadIdx.x & 63;
    int d = blockIdx.x * 4 + wid;
    int lo = rowptr[d], hi = rowptr[d + 1];
    int g = yb[d];
    const unsigned short* Gl = G + lane * CPL;
    float acc[CPL];
    {
        unsigned short sv[CPL];
        if (CPL == 4) *(uint2*)sv = *(const uint2*)(Gl + (size_t)d * STR);
        else          *(unsigned int*)sv = *(const unsigned int*)(Gl + (size_t)d * STR);
#pragma unroll
        for (int c = 0; c < CPL; ++c) acc[c] = bf2f(sv[c]);
    }
    int e = lo;
    for (; e + 1 < hi; e += 2){
        int pkA = eidx[e], pkB = eidx[e + 1];
        int sA = pkA & 0x0FFFFFFF, rA = pkA >> 28;
        int sB = pkB & 0x0FFFFFFF, rB = pkB >> 28;
        const unsigned short* ga = Gl + (size_t)sA * STR + (1 + rA) * DOUT;
        const unsigned short* gb = Gl + (size_t)sB * STR + (1 + rB) * DOUT;
        unsigned short vA[CPL], vB[CPL];
        if (CPL == 4){ *(uint2*)vA = *(const uint2*)ga; *(uint2*)vB = *(const uint2*)gb; }
        else { *(unsigned int*)vA = *(const unsigned int*)ga; *(unsigned int*)vB = *(const unsigned int*)gb; }
#pragma unroll
        for (int c = 0; c < CPL; ++c) acc[c] += bf2f(vA[c]) + bf2f(vB[c]);
    }
    if (e < hi){
        int pk = eidx[e];
        int s = pk & 0x0FFFFFFF, r = pk >> 28;
        const unsigned short* ga = Gl + (size_t)s * STR + (1 + r) * DOUT;
        unsigned short v[CPL];
        if (CPL == 4) *(uint2*)v = *(const uint2*)ga;
        else          *(unsigned int*)v = *(const unsigned int*)ga;
#pragma unroll
        for (int c = 0; c < CPL; ++c) acc[c] += bf2f(v[c]);
    }
    const float* cb = ctxb + (size_t)g * DOUT + lane * CPL;
    float f[CPL];
    unsigned short o[CPL];
#pragma unroll
    for (int c = 0; c < CPL; ++c){ f[c] = fmaxf(acc[c] + cb[c], 0.f); o[c] = f2bf(f[c]); }
    unsigned short* ho = hout + (size_t)d * DOUT + lane * CPL;
    if (CPL == 4) *(uint2*)ho = *(uint2*)o; else *(unsigned int*)ho = *(unsigned int*)o;
    if (OUTF){
        float* fo = fout + (size_t)d * DOUT + lane * CPL;
        if (CPL == 4){ float4 q = {f[0], f[1], f[2], f[3]}; *(float4*)fo = q; }
        else { float2 q = {f[0], f[1]}; *(float2*)fo = q; }
    }
}

// 128x128-tile LDS-staged bf16 MFMA GEMM, BK=64, double-buffered, 8 waves.
// Swapped-operand MFMA; epilogue through PADDED LDS C-tile (row stride 136 elems
// = 272B: write bank = (4*rl+2*g)%32 -> 2-way only; reads 16B-aligned b128),
// then contiguous 256B row-segment global stores.
template<int KTOT, int DIN, int NYT, bool HAS_S, bool RELUCTX>
__global__ __launch_bounds__(512, 4) void gemm128(
        const unsigned short* __restrict__ hA,
        const unsigned short* __restrict__ S,
        const unsigned short* __restrict__ WT,
        const float* __restrict__ ctxb,
        const int* __restrict__ yb,
        unsigned short* __restrict__ outb,
        int outstride, int ctxstride){
    __shared__ unsigned short lds[2][2][128 * 64];
    constexpr int NT = KTOT / 64;
    constexpr int CSTR = 136;                // padded C-tile row stride (elems)
    int tid = threadIdx.x;
    int wid = tid >> 6, lane = tid & 63;
    int l15 = lane & 15, lk = lane >> 4;
    int wr = wid >> 2, wc = wid & 3;

    int nwg = gridDim.x;
    int orig = blockIdx.x;
    int q = nwg >> 3, r8 = nwg & 7;
    int xcd = orig & 7, pos = orig >> 3;
    int wg = (xcd < r8 ? xcd * (q + 1) : r8 * (q + 1) + (xcd - r8) * q) + pos;
    int mrow0 = (wg / NYT) * 128;
    int ncol0 = (wg % NYT) * 128;

    f32x4 acc[4][2];
#pragma unroll
    for (int m = 0; m < 4; ++m)
#pragma unroll
        for (int n = 0; n < 2; ++n) acc[m][n] = (f32x4){0.f, 0.f, 0.f, 0.f};

    auto stage = [&](int kt, int buf){
#pragma unroll
        for (int i = 0; i < 2; ++i){
            int idx = i * 512 + tid;
            int r = idx >> 3;
            int cbl = idx & 7;
            int cb = cbl ^ (r & 7);
            int k0 = kt * 64 + cb * 8;
            int gr = mrow0 + r; if (gr > NN - 1) gr = NN - 1;
            const unsigned short* ga;
            if (HAS_S && kt >= DIN / 64) ga = S + (size_t)gr * (4 * DIN) + (k0 - DIN);
            else                         ga = hA + (size_t)gr * DIN + k0;
            GLDS16(ga, &lds[buf][0][(size_t)(i * 8 + wid) * 512]);
            int gj = ncol0 + r;
            const unsigned short* gb = WT + (size_t)gj * KTOT + k0;
            GLDS16(gb, &lds[buf][1][(size_t)(i * 8 + wid) * 512]);
        }
    };

    stage(0, 0);
    __syncthreads();
    int buf = 0;
#pragma unroll 1
    for (int kt = 0; kt < NT; ++kt){
        if (kt + 1 < NT) stage(kt + 1, buf ^ 1);
#pragma unroll
        for (int ks = 0; ks < 2; ++ks){
            int c = ks * 4 + lk;
            bf16x8 a[4], b[2];
#pragma unroll
            for (int m = 0; m < 4; ++m){
                int r = wr * 64 + m * 16 + l15;
                a[m] = *(const bf16x8*)&lds[buf][0][r * 64 + (c ^ (r & 7)) * 8];
            }
#pragma unroll
            for (int n = 0; n < 2; ++n){
                int j = wc * 32 + n * 16 + l15;
                b[n] = *(const bf16x8*)&lds[buf][1][j * 64 + (c ^ (j & 7)) * 8];
            }
#pragma unroll
            for (int m = 0; m < 4; ++m)
#pragma unroll
                for (int n = 0; n < 2; ++n)
                    acc[m][n] = __builtin_amdgcn_mfma_f32_16x16x32_bf16(b[n], a[m], acc[m][n], 0, 0, 0);
        }
        __syncthreads();
        buf ^= 1;
    }

    // epilogue: fragments -> padded LDS C-tile -> contiguous 256B-row stores
    unsigned short* ldsC = &lds[0][0][0];   // 128 x 136 elems = 34.8 KB
#pragma unroll
    for (int m = 0; m < 4; ++m){
        int rl = wr * 64 + m * 16 + l15;
        int row = mrow0 + rl;
        const float* cb = RELUCTX ? (ctxb + (size_t)yb[row < NN ? row : NN - 1] * ctxstride) : ctxb;
#pragma unroll
        for (int n = 0; n < 2; ++n){
            int g = wc * 8 + n * 4 + lk;     // granule (4 elems) 0..31
            unsigned short o[4];
#pragma unroll
            for (int r = 0; r < 4; ++r){
                float v = acc[m][n][r] + cb[ncol0 + g * 4 + r];
                if (RELUCTX) v = fmaxf(v, 0.f);
                o[r] = f2bf(v);
            }
            *(uint2*)&ldsC[rl * CSTR + g * 4] = *(uint2*)o;
        }
    }
    __syncthreads();
#pragma unroll
    for (int i = 0; i < 4; ++i){
        int idx = i * 512 + tid;             // 128 rows x 16 chunks(8 elems)
        int rl = idx >> 4;
        int c = idx & 15;
        bf16x8 v = *(const bf16x8*)&ldsC[rl * CSTR + c * 8];
        int row = mrow0 + rl;
        if (row < NN)
            *(bf16x8*)(outb + (size_t)row * outstride + ncol0 + c * 8) = v;
    }
}

// Fused y_pred = log_softmax(ybf @ WTz^T + lzb)
__global__ __launch_bounds__(512, 2) void logit_lsm_kernel(
        const unsigned short* __restrict__ ybf,
        const unsigned short* __restrict__ WTz,
        const float* __restrict__ lzb,
        float* __restrict__ ypred){
    __shared__ unsigned short ldsB[2][VV * 32];
    __shared__ float lzbs[VV];
    __shared__ float pm[4][16][2], ps[4][16][2];
    int tid = threadIdx.x;
    int wid = tid >> 6, lane = tid & 63;
    int l15 = lane & 15, lk = lane >> 4;
    int wr = wid >> 1, wc = wid & 1;
    int row = blockIdx.x * 64 + wr * 16 + l15;

    lzbs[tid] = lzb[tid];

    bf16x8 aR[4];
    const unsigned short* ap = ybf + (size_t)row * EMB;
#pragma unroll
    for (int kt = 0; kt < 4; ++kt) aR[kt] = *(const bf16x8*)(ap + kt * 32 + lk * 8);

    auto stageB = [&](int kt, int buf){
#pragma unroll
        for (int i = 0; i < 4; ++i){
            int idx = i * 512 + tid;
            int j = idx >> 2;
            int cbl = idx & 3;
            int cb = cbl ^ (j & 3);
            const unsigned short* gb = WTz + (size_t)j * EMB + kt * 32 + cb * 8;
            GLDS16(gb, &ldsB[buf][(size_t)(i * 8 + wid) * 512]);
        }
    };

    f32x4 acc[16];
#pragma unroll
    for (int n = 0; n < 16; ++n) acc[n] = (f32x4){0.f, 0.f, 0.f, 0.f};

    stageB(0, 0);
    __syncthreads();
    int buf = 0;
#pragma unroll
    for (int kt = 0; kt < 4; ++kt){
        if (kt < 3) stageB(kt + 1, buf ^ 1);
#pragma unroll
        for (int nh = 0; nh < 2; ++nh){
            bf16x8 b[8];
#pragma unroll
            for (int n8 = 0; n8 < 8; ++n8){
                int j = wc * 256 + (nh * 8 + n8) * 16 + l15;
                b[n8] = *(const bf16x8*)&ldsB[buf][j * 32 + ((lk ^ (j & 3)) * 8)];
            }
#pragma unroll
            for (int n8 = 0; n8 < 8; ++n8)
                acc[nh * 8 + n8] = __builtin_amdgcn_mfma_f32_16x16x32_bf16(b[n8], aR[kt], acc[nh * 8 + n8], 0, 0, 0);
        }
        __syncthreads();
        buf ^= 1;
    }

    float m = -3.0e38f;
#pragma unroll
    for (int n = 0; n < 16; ++n){
        int colb = wc * 256 + n * 16 + lk * 4;
#pragma unroll
        for (int r = 0; r < 4; ++r){
            float v = acc[n][r] + lzbs[colb + r];
            acc[n][r] = v;
            m = fmaxf(m, v);
        }
    }
    m = fmaxf(m, __shfl_xor(m, 16));
    m = fmaxf(m, __shfl_xor(m, 32));
    float s = 0.f;
#pragma unroll
    for (int n = 0; n < 16; ++n)
#pragma unroll
        for (int r = 0; r < 4; ++r) s += expf(acc[n][r] - m);
    s += __shfl_xor(s, 16);
    s += __shfl_xor(s, 32);
    if (lk == 0){ pm[wr][l15][wc] = m; ps[wr][l15][wc] = s; }
    __syncthreads();
    float m0 = pm[wr][l15][0], m1 = pm[wr][l15][1];
    float s0 = ps[wr][l15][0], s1 = ps[wr][l15][1];
    float M = fmaxf(m0, m1);
    float l = M + logf(expf(m0 - M) * s0 + expf(m1 - M) * s1);

    float* orow = ypred + (size_t)row * VV + wc * 256;
#pragma unroll
    for (int n = 0; n < 16; ++n){
        int colb = n * 16 + lk * 4;
        float4 q = {acc[n][0] - l, acc[n][1] - l, acc[n][2] - l, acc[n][3] - l};
        *(float4*)(orow + colb) = q;
    }
}

// ---- edge head, factored ----
__global__ __launch_bounds__(256) void zpair_kernel(const float* __restrict__ y,
        const float* __restrict__ Wg, float* __restrict__ z){
    __shared__ float ylds[16][132];
    __shared__ float wg[2 * EMB * NSRT];
    for (int i = threadIdx.x; i < 2 * EMB * NSRT; i += 256) wg[i] = Wg[i];
    int n0 = blockIdx.x * 16;
    for (int i = threadIdx.x; i < 16 * 32; i += 256){
        int node = i >> 5, f4 = i & 31;
        *(float4*)&ylds[node][f4 * 4] = *(const float4*)(y + (size_t)(n0 + node) * EMB + f4 * 4);
    }
    __syncthreads();
    int t = threadIdx.x;
    if (t < 160){
        int node = t & 15, c = t >> 4;
        int base = (c >= 5) ? EMB : 0;
        int cc = (c >= 5) ? c - 5 : c;
        float acc = 0.f;
#pragma unroll 4
        for (int k = 0; k < EMB; ++k) acc += ylds[node][k] * wg[(base + k) * NSRT + cc];
        z[(size_t)(n0 + node) * 10 + c] = acc;
    }
}

__global__ __launch_bounds__(256) void edge2_kernel(const int* __restrict__ src,
        const int* __restrict__ dst, const float* __restrict__ z,
        const float* __restrict__ bg, float* __restrict__ out){
    int e = blockIdx.x * 256 + threadIdx.x; if (e >= EE) return;
    int s = src[e], d = dst[e];
    const float* zs = z + (size_t)s * 10;
    const float* zd = z + (size_t)d * 10 + 5;
    float l0 = zs[0] + zd[0] + bg[0];
    float l1 = zs[1] + zd[1] + bg[1];
    float l2 = zs[2] + zd[2] + bg[2];
    float l3 = zs[3] + zd[3] + bg[3];
    float l4 = zs[4] + zd[4] + bg[4];
    float m = fmaxf(fmaxf(fmaxf(l0, l1), fmaxf(l2, l3)), l4);
    float ssum = expf(l0 - m) + expf(l1 - m) + expf(l2 - m) + expf(l3 - m) + expf(l4 - m);
    float lg = m + logf(ssum);
    float* o = out + (size_t)e * NSRT;
    o[0] = l0 - lg; o[1] = l1 - lg; o[2] = l2 - lg; o[3] = l3 - lg; o[4] = l4 - lg;
}

__global__ __launch_bounds__(256) void i2f_kernel(const int* __restrict__ in,
        float* __restrict__ out, int n){
    int i = blockIdx.x * 256 + threadIdx.x;
    if (i < n) out[i] = (float)in[i];
}

extern "C" void kernel_launch(void* const* d_in, const int* in_sizes, int n_in,
                              void* d_out, int out_size, void* d_ws, size_t ws_size,
                              hipStream_t stream){
    const float* x    = (const float*)d_in[0];
    const int*   xb   = (const int*)d_in[1];
    const int*   ty   = (const int*)d_in[2];
    const int*   ei   = (const int*)d_in[3];
    const int*   et   = (const int*)d_in[4];
    const int*   tyb  = (const int*)d_in[5];
    const float* emb  = (const float*)d_in[6];
    const float* Ws1 = (const float*)d_in[7],  *Wr1 = (const float*)d_in[8];
    const float* Wc1 = (const float*)d_in[9],  *b1  = (const float*)d_in[10];
    const float* Ws2 = (const float*)d_in[11], *Wr2 = (const float*)d_in[12];
    const float* Wc2 = (const float*)d_in[13], *b2  = (const float*)d_in[14];
    const float* Ws3 = (const float*)d_in[15], *Wr3 = (const float*)d_in[16];
    const float* Wc3 = (const float*)d_in[17], *b3  = (const float*)d_in[18];
    const float* lzw = (const float*)d_in[19], *lzb = (const float*)d_in[20];
    const float* lgw = (const float*)d_in[21], *lgb = (const float*)d_in[22];

    const int* src = ei;
    const int* dst = ei + EE;

    float* out = (float*)d_out;
    const size_t OFF_Y  = 0;
    const size_t OFF_EI = (size_t)NN * EMB;
    const size_t OFF_ET = OFF_EI + 2 * (size_t)EE;
    const size_t OFF_YP = OFF_ET + (size_t)EE;
    const size_t OFF_EP = OFF_YP + (size_t)NN * VV;

    char* w = (char*)d_ws;
    auto alloc = [&](size_t bytes){ char* p = w; w += (bytes + 255) & ~(size_t)255; return p; };
    unsigned short* h0  = (unsigned short*)alloc((size_t)NN * EMB * 2);
    unsigned short* h1  = (unsigned short*)alloc((size_t)NN * HH * 2);
    unsigned short* h2  = (unsigned short*)alloc((size_t)NN * HH * 2);
    unsigned short* ybf = (unsigned short*)alloc((size_t)NN * EMB * 2);
    unsigned short* G2  = (unsigned short*)alloc((size_t)NN * 5 * HH * 2);
    unsigned short* G3  = (unsigned short*)alloc((size_t)NN * 5 * EMB * 2);
    unsigned short* WT1 = (unsigned short*)alloc((size_t)HH * (5 * EMB) * 2);
    unsigned short* WT2p= (unsigned short*)alloc((size_t)(5 * HH) * HH * 2);
    unsigned short* WT3p= (unsigned short*)alloc((size_t)(5 * EMB) * HH * 2);
    unsigned short* WTz = (unsigned short*)alloc((size_t)VV * EMB * 2);
    float* ctxs  = (float*)alloc(BB * F_IN * 4);
    float* ctx   = (float*)alloc(BB * F_IN * 4);
    float* ctxb1 = (float*)alloc(BB * HH * 4);
    float* ctxb2 = (float*)alloc(BB * HH * 4);
    float* ctxb3 = (float*)alloc(BB * EMB * 4);
    float* zpair = (float*)alloc((size_t)NN * 10 * 4);
    float* zerob = (float*)alloc((size_t)5 * HH * 4);
    int* deg    = (int*)alloc((size_t)NN * 4);
    int* rowptr = (int*)alloc(((size_t)NN + 1) * 4);
    int* cursor = (int*)alloc((size_t)NN * 4);
    int* eidx   = (int*)alloc((size_t)EE * 4);
    int* bsum   = (int*)alloc((size_t)SNB * 4);
    int* boff   = (int*)alloc((size_t)SNB * 4);

    // y_pred region of d_out doubles as S scratch (layer 1 only) until logit_lsm
    unsigned short* Sbuf = (unsigned short*)(out + OFF_YP);

    // CSR by dst
    hipMemsetAsync(deg, 0, (size_t)NN * 4, stream);
    hipMemsetAsync(zerob, 0, (size_t)5 * HH * 4, stream);
    hist_kernel<<<(EE + 255) / 256, 256, 0, stream>>>(dst, deg);
    scanA_kernel<<<SNB, 256, 0, stream>>>(deg, bsum);
    scanB_kernel<<<1, 256, 0, stream>>>(bsum, boff);
    scanC_kernel<<<SNB, 256, 0, stream>>>(deg, boff, rowptr, cursor);
    fill_kernel<<<(EE + 255) / 256, 256, 0, stream>>>(src, dst, et, cursor, eidx);

    // ctx + folded ctx@Wc+b tables
    hipMemsetAsync(ctxs, 0, BB * F_IN * 4, stream);
    ctxsum_kernel<<<(MM + CTX_RPB - 1) / CTX_RPB, 256, 0, stream>>>(x, xb, ctxs);
    ctxdiv_kernel<<<BB, 256, 0, stream>>>(ctxs, xb, ctx);
    ctxb_kernel<<<dim3(BB, HH / 64), 64, 0, stream>>>(ctx, Wc1, b1, ctxb1, HH);
    ctxb_kernel<<<dim3(BB, HH / 64), 64, 0, stream>>>(ctx, Wc2, b2, ctxb2, HH);
    ctxb_kernel<<<dim3(BB, EMB / 64), 64, 0, stream>>>(ctx, Wc3, b3, ctxb3, EMB);

    // weight stacks
    build_wt<<<(HH * 5 * EMB + 255) / 256, 256, 0, stream>>>(Ws1, Wr1, WT1, EMB, HH, 5 * EMB);
    build_wtp<<<(5 * HH * HH + 255) / 256, 256, 0, stream>>>(Ws2, Wr2, WT2p, HH, HH);
    build_wtp<<<(5 * EMB * HH + 255) / 256, 256, 0, stream>>>(Ws3, Wr3, WT3p, HH, EMB);
    build_wt<<<(VV * EMB + 255) / 256, 256, 0, stream>>>(lzw, lzw, WTz, EMB, VV, EMB);

    // h0 = embeds[tgt_y].sum(1)
    embed_kernel<<<NN * EMB / 256, 256, 0, stream>>>(ty, emb, h0);

    const int MT = (NN + 127) / 128;  // 1563

    // layer 1: aggregate in din-space then fat GEMM (KTOT=640)
    sbuild_kernel<EMB><<<NN / 4, 256, 0, stream>>>(h0, rowptr, eidx, Sbuf);
    gemm128<640, 128, 2, true, true><<<MT * 2, 512, 0, stream>>>(
        h0, Sbuf, WT1, ctxb1, tyb, h1, HH, HH);

    // layer 2: project-first -> aggregate in dout-space
    gemm128<256, 256, 10, false, false><<<MT * 10, 512, 0, stream>>>(
        h1, nullptr, WT2p, zerob, nullptr, G2, 5 * HH, 0);
    agg_kernel<HH, false><<<NN / 4, 256, 0, stream>>>(
        G2, rowptr, eidx, ctxb2, tyb, h2, nullptr);

    // layer 3: project-first -> aggregate, dual f32+bf16 out
    gemm128<256, 256, 5, false, false><<<MT * 5, 512, 0, stream>>>(
        h2, nullptr, WT3p, zerob, nullptr, G3, 5 * EMB, 0);
    agg_kernel<EMB, true><<<NN / 4, 256, 0, stream>>>(
        G3, rowptr, eidx, ctxb3, tyb, ybf, out + OFF_Y);

    // edge head tables
    zpair_kernel<<<NN / 16, 256, 0, stream>>>(out + OFF_Y, lgw, zpair);

    // y_pred = log_softmax(y @ lin_z_w + lin_z_b), fused
    logit_lsm_kernel<<<NN / 64, 512, 0, stream>>>(ybf, WTz, lzb, out + OFF_YP);

    // per-edge head
    edge2_kernel<<<(EE + 255) / 256, 256, 0, stream>>>(src, dst, zpair, lgb, out + OFF_EP);
    i2f_kernel<<<(2 * EE + 255) / 256, 256, 0, stream>>>(ei, out + OFF_EI, 2 * EE);
    i2f_kernel<<<(EE + 255) / 256, 256, 0, stream>>>(et, out + OFF_ET, EE);
}

// Round 15
// 1387.239 us; speedup vs baseline: 1.0482x; 1.0000x over previous
//
#include <hip/hip_runtime.h>
#include <hip/hip_bf16.h>
#include <stdint.h>

#define NN 200000
#define MM 100000
#define EE 600000
#define BB 64
#define F_IN 256
#define HH 256
#define EMB 128
#define VV 512
#define NSRT 5

typedef __attribute__((ext_vector_type(8))) short bf16x8;
typedef __attribute__((ext_vector_type(4))) float f32x4;

__device__ __forceinline__ unsigned short f2bf(float x){
    union { float f; unsigned int u; } c; c.f = x;
    unsigned int r = c.u + 0x7FFFu + ((c.u >> 16) & 1u);
    return (unsigned short)(r >> 16);
}
__device__ __forceinline__ float bf2f(unsigned short b){
    union { unsigned int u; float f; } c; c.u = ((unsigned int)b) << 16;
    return c.f;
}

__device__ __forceinline__ int lowerb(const int* a, int n, int key){
    int lo = 0, hi = n;
    while (lo < hi){ int mid = (lo + hi) >> 1; if (a[mid] < key) lo = mid + 1; else hi = mid; }
    return lo;
}

#define GLDS16(g, l) __builtin_amdgcn_global_load_lds( \
    (const __attribute__((address_space(1))) unsigned int*)(g), \
    (__attribute__((address_space(3))) unsigned int*)(l), 16, 0, 0)

// ---- per-graph mean of x ----
#define CTX_RPB 128
__global__ __launch_bounds__(256) void ctxsum_kernel(const float* __restrict__ x,
        const int* __restrict__ xb, float* __restrict__ sum){
    int r0 = blockIdx.x * CTX_RPB;
    int r1 = r0 + CTX_RPB; if (r1 > MM) r1 = MM;
    int t = threadIdx.x;
    float s = 0.f;
    int g = xb[r0];
    for (int r = r0; r < r1; ++r){
        int gb = xb[r];
        if (gb != g){ atomicAdd(&sum[g * F_IN + t], s); s = 0.f; g = gb; }
        s += x[(size_t)r * F_IN + t];
    }
    atomicAdd(&sum[g * F_IN + t], s);
}

__global__ __launch_bounds__(256) void ctxdiv_kernel(const float* __restrict__ sum,
        const int* __restrict__ xb, float* __restrict__ ctx){
    int g = blockIdx.x, t = threadIdx.x;
    int lo = lowerb(xb, MM, g), hi = lowerb(xb, MM, g + 1);
    int c = hi - lo; if (c < 1) c = 1;
    ctx[g * F_IN + t] = sum[g * F_IN + t] / (float)c;
}

__global__ __launch_bounds__(64) void ctxb_kernel(const float* __restrict__ ctx,
        const float* __restrict__ Wc, const float* __restrict__ b,
        float* __restrict__ out, int dout){
    int g = blockIdx.x; int j = blockIdx.y * 64 + threadIdx.x;
    float acc = b[j];
    const float* cr = ctx + g * F_IN;
    for (int k = 0; k < F_IN; ++k) acc += cr[k] * Wc[(size_t)k * dout + j];
    out[(size_t)g * dout + j] = acc;
}

// WT[j][k] (K-stacked form)
__global__ __launch_bounds__(256) void build_wt(const float* __restrict__ Ws,
        const float* __restrict__ Wr, unsigned short* __restrict__ WT,
        int din, int dout, int ktot){
    size_t idx = (size_t)blockIdx.x * 256 + threadIdx.x;
    size_t total = (size_t)dout * ktot;
    if (idx >= total) return;
    int j = (int)(idx / ktot), k = (int)(idx % ktot);
    float v = (k < din) ? Ws[(size_t)k * dout + j] : Wr[(size_t)(k - din) * dout + j];
    WT[idx] = f2bf(v);
}

// WTp[jj][k] (N-stacked form)
__global__ __launch_bounds__(256) void build_wtp(const float* __restrict__ Ws,
        const float* __restrict__ Wr, unsigned short* __restrict__ WT,
        int K, int dout){
    size_t idx = (size_t)blockIdx.x * 256 + threadIdx.x;
    size_t total = (size_t)5 * dout * K;
    if (idx >= total) return;
    int jj = (int)(idx / K), k = (int)(idx % K);
    int blk = jj / dout, j = jj % dout;
    float v = (blk == 0) ? Ws[(size_t)k * dout + j]
                         : Wr[((size_t)(blk - 1) * K + k) * dout + j];
    WT[idx] = f2bf(v);
}

__global__ __launch_bounds__(256) void embed_kernel(const int* __restrict__ ty,
        const float* __restrict__ emb, unsigned short* __restrict__ h0){
    size_t idx = (size_t)blockIdx.x * 256 + threadIdx.x;
    int i = (int)(idx >> 7), c = (int)(idx & 127);
    int t0 = ty[i * 3], t1 = ty[i * 3 + 1], t2 = ty[i * 3 + 2];
    float v = emb[(size_t)t0 * EMB + c] + emb[(size_t)t1 * EMB + c] + emb[(size_t)t2 * EMB + c];
    h0[idx] = f2bf(v);
}

__global__ __launch_bounds__(256) void hist_kernel(const int* __restrict__ dst, int* __restrict__ deg){
    int e = blockIdx.x * 256 + threadIdx.x; if (e >= EE) return;
    atomicAdd(&deg[dst[e]], 1);
}

#define SNB ((NN + 1023) / 1024)

__global__ __launch_bounds__(256) void scanA_kernel(const int* __restrict__ deg,
        int* __restrict__ bsum){
    __shared__ int wsum[4];
    int tid = threadIdx.x, wid = tid >> 6, lane = tid & 63;
    int base = blockIdx.x * 1024 + tid * 4;
    int s = 0;
    if (base + 3 < NN){ int4 v = *(const int4*)(deg + base); s = v.x + v.y + v.z + v.w; }
    else { for (int i = 0; i < 4; ++i){ int idx = base + i; if (idx < NN) s += deg[idx]; } }
#pragma unroll
    for (int off = 1; off < 64; off <<= 1) s += __shfl_xor(s, off);
    if (lane == 0) wsum[wid] = s;
    __syncthreads();
    if (tid == 0) bsum[blockIdx.x] = wsum[0] + wsum[1] + wsum[2] + wsum[3];
}

__global__ __launch_bounds__(256) void scanB_kernel(const int* __restrict__ bsum,
        int* __restrict__ boff){
    __shared__ int lds[256];
    int t = threadIdx.x;
    int v = (t < SNB) ? bsum[t] : 0;
    lds[t] = v; __syncthreads();
    for (int off = 1; off < 256; off <<= 1){
        int n = (t >= off) ? lds[t - off] : 0;
        __syncthreads();
        lds[t] += n;
        __syncthreads();
    }
    if (t < SNB) boff[t] = lds[t] - v;
}

__global__ __launch_bounds__(256) void scanC_kernel(const int* __restrict__ deg,
        const int* __restrict__ boff, int* __restrict__ rowptr, int* __restrict__ cursor){
    __shared__ int wsum[4];
    int tid = threadIdx.x, wid = tid >> 6, lane = tid & 63;
    int base = blockIdx.x * 1024 + tid * 4;
    int d0 = 0, d1 = 0, d2 = 0, d3 = 0;
    if (base + 3 < NN){ int4 v = *(const int4*)(deg + base); d0 = v.x; d1 = v.y; d2 = v.z; d3 = v.w; }
    else if (base < NN){
        d0 = deg[base];
        if (base + 1 < NN) d1 = deg[base + 1];
        if (base + 2 < NN) d2 = deg[base + 2];
    }
    int tsum = d0 + d1 + d2 + d3;
    int run = tsum;
#pragma unroll
    for (int off = 1; off < 64; off <<= 1){
        int n = __shfl_up(run, off);
        if (lane >= off) run += n;
    }
    if (lane == 63) wsum[wid] = run;
    int texcl = run - tsum;
    __syncthreads();
    int woff = 0;
    for (int i = 0; i < wid; ++i) woff += wsum[i];
    int p = boff[blockIdx.x] + woff + texcl;
    if (base < NN){
        rowptr[base] = p; cursor[base] = p; p += d0;
        if (base + 1 < NN){ rowptr[base + 1] = p; cursor[base + 1] = p; p += d1; }
        if (base + 2 < NN){ rowptr[base + 2] = p; cursor[base + 2] = p; p += d2; }
        if (base + 3 < NN){ rowptr[base + 3] = p; cursor[base + 3] = p; p += d3; }
    }
    if (blockIdx.x == 0 && tid == 0) rowptr[NN] = EE;
}

__global__ __launch_bounds__(256) void fill_kernel(const int* __restrict__ src,
        const int* __restrict__ dst, const int* __restrict__ et,
        int* __restrict__ cursor, int* __restrict__ eidx){
    int e = blockIdx.x * 256 + threadIdx.x; if (e >= EE) return;
    int p = atomicAdd(&cursor[dst[e]], 1);
    eidx[p] = src[e] | (et[e] << 28);
}

// S[d][r][:] = sum of h[src] over incoming edges of type r
template<int DIN>
__global__ __launch_bounds__(256) void sbuild_kernel(const unsigned short* __restrict__ h,
        const int* __restrict__ rowptr, const int* __restrict__ eidx,
        unsigned short* __restrict__ S){
    constexpr int CPL = DIN / 64;
    int wid = threadIdx.x >> 6, lane = threadIdx.x & 63;
    int d = blockIdx.x * 4 + wid;
    int lo = rowptr[d], hi = rowptr[d + 1];
    float acc0[CPL], acc1[CPL], acc2[CPL], acc3[CPL];
#pragma unroll
    for (int c = 0; c < CPL; ++c){ acc0[c] = 0.f; acc1[c] = 0.f; acc2[c] = 0.f; acc3[c] = 0.f; }
    const unsigned short* hl = h + lane * CPL;
    int e = lo;
    for (; e + 1 < hi; e += 2){
        int pkA = eidx[e], pkB = eidx[e + 1];
        int sA = pkA & 0x0FFFFFFF, rA = pkA >> 28;
        int sB = pkB & 0x0FFFFFFF, rB = pkB >> 28;
        unsigned short vA[CPL], vB[CPL];
        if (CPL == 4){
            *(uint2*)vA = *(const uint2*)(hl + (size_t)sA * DIN);
            *(uint2*)vB = *(const uint2*)(hl + (size_t)sB * DIN);
        } else {
            *(unsigned int*)vA = *(const unsigned int*)(hl + (size_t)sA * DIN);
            *(unsigned int*)vB = *(const unsigned int*)(hl + (size_t)sB * DIN);
        }
        float a0 = (rA == 0) ? 1.f : 0.f, a1 = (rA == 1) ? 1.f : 0.f;
        float a2 = (rA == 2) ? 1.f : 0.f, a3 = (rA == 3) ? 1.f : 0.f;
        float b0 = (rB == 0) ? 1.f : 0.f, b1 = (rB == 1) ? 1.f : 0.f;
        float b2 = (rB == 2) ? 1.f : 0.f, b3 = (rB == 3) ? 1.f : 0.f;
#pragma unroll
        for (int c = 0; c < CPL; ++c){
            float fA = bf2f(vA[c]), fB = bf2f(vB[c]);
            acc0[c] += a0 * fA + b0 * fB;
            acc1[c] += a1 * fA + b1 * fB;
            acc2[c] += a2 * fA + b2 * fB;
            acc3[c] += a3 * fA + b3 * fB;
        }
    }
    if (e < hi){
        int pk = eidx[e];
        int s = pk & 0x0FFFFFFF, r = pk >> 28;
        unsigned short v[CPL];
        if (CPL == 4) *(uint2*)v = *(const uint2*)(hl + (size_t)s * DIN);
        else          *(unsigned int*)v = *(const unsigned int*)(hl + (size_t)s * DIN);
        float m0 = (r == 0) ? 1.f : 0.f, m1 = (r == 1) ? 1.f : 0.f;
        float m2 = (r == 2) ? 1.f : 0.f, m3 = (r == 3) ? 1.f : 0.f;
#pragma unroll
        for (int c = 0; c < CPL; ++c){
            float f = bf2f(v[c]);
            acc0[c] += m0 * f; acc1[c] += m1 * f; acc2[c] += m2 * f; acc3[c] += m3 * f;
        }
    }
    unsigned short* So = S + (size_t)d * 4 * DIN + lane * CPL;
    unsigned short o[CPL];
#pragma unroll
    for (int c = 0; c < CPL; ++c) o[c] = f2bf(acc0[c]);
    if (CPL == 4) *(uint2*)(So) = *(uint2*)o; else *(unsigned int*)(So) = *(unsigned int*)o;
#pragma unroll
    for (int c = 0; c < CPL; ++c) o[c] = f2bf(acc1[c]);
    if (CPL == 4) *(uint2*)(So + DIN) = *(uint2*)o; else *(unsigned int*)(So + DIN) = *(unsigned int*)o;
#pragma unroll
    for (int c = 0; c < CPL; ++c) o[c] = f2bf(acc2[c]);
    if (CPL == 4) *(uint2*)(So + 2 * DIN) = *(uint2*)o; else *(unsigned int*)(So + 2 * DIN) = *(unsigned int*)o;
#pragma unroll
    for (int c = 0; c < CPL; ++c) o[c] = f2bf(acc3[c]);
    if (CPL == 4) *(uint2*)(So + 3 * DIN) = *(uint2*)o; else *(unsigned int*)(So + 3 * DIN) = *(unsigned int*)o;
}

// out[d] = relu(G[d][self] + sum_{e->d} G[src_e][(1+r)*DOUT] + ctxb[yb[d]])
template<int DOUT, bool OUTF>
__global__ __launch_bounds__(256) void agg_kernel(const unsigned short* __restrict__ G,
        const int* __restrict__ rowptr, const int* __restrict__ eidx,
        const float* __restrict__ ctxb, const int* __restrict__ yb,
        unsigned short* __restrict__ hout, float* __restrict__ fout){
    constexpr int CPL = DOUT / 64;
    constexpr int STR = 5 * DOUT;
    int wid = threadIdx.x >> 6, lane = threadIdx.x & 63;
    int d = blockIdx.x * 4 + wid;
    int lo = rowptr[d], hi = rowptr[d + 1];
    int g = yb[d];
    const unsigned short* Gl = G + lane * CPL;
    float acc[CPL];
    {
        unsigned short sv[CPL];
        if (CPL == 4) *(uint2*)sv = *(const uint2*)(Gl + (size_t)d * STR);
        else          *(unsigned int*)sv = *(const unsigned int*)(Gl + (size_t)d * STR);
#pragma unroll
        for (int c = 0; c < CPL; ++c) acc[c] = bf2f(sv[c]);
    }
    int e = lo;
    for (; e + 1 < hi; e += 2){
        int pkA = eidx[e], pkB = eidx[e + 1];
        int sA = pkA & 0x0FFFFFFF, rA = pkA >> 28;
        int sB = pkB & 0x0FFFFFFF, rB = pkB >> 28;
        const unsigned short* ga = Gl + (size_t)sA * STR + (1 + rA) * DOUT;
        const unsigned short* gb = Gl + (size_t)sB * STR + (1 + rB) * DOUT;
        unsigned short vA[CPL], vB[CPL];
        if (CPL == 4){ *(uint2*)vA = *(const uint2*)ga; *(uint2*)vB = *(const uint2*)gb; }
        else { *(unsigned int*)vA = *(const unsigned int*)ga; *(unsigned int*)vB = *(const unsigned int*)gb; }
#pragma unroll
        for (int c = 0; c < CPL; ++c) acc[c] += bf2f(vA[c]) + bf2f(vB[c]);
    }
    if (e < hi){
        int pk = eidx[e];
        int s = pk & 0x0FFFFFFF, r = pk >> 28;
        const unsigned short* ga = Gl + (size_t)s * STR + (1 + r) * DOUT;
        unsigned short v[CPL];
        if (CPL == 4) *(uint2*)v = *(const uint2*)ga;
        else          *(unsigned int*)v = *(const unsigned int*)ga;
#pragma unroll
        for (int c = 0; c < CPL; ++c) acc[c] += bf2f(v[c]);
    }
    const float* cb = ctxb + (size_t)g * DOUT + lane * CPL;
    float f[CPL];
    unsigned short o[CPL];
#pragma unroll
    for (int c = 0; c < CPL; ++c){ f[c] = fmaxf(acc[c] + cb[c], 0.f); o[c] = f2bf(f[c]); }
    unsigned short* ho = hout + (size_t)d * DOUT + lane * CPL;
    if (CPL == 4) *(uint2*)ho = *(uint2*)o; else *(unsigned int*)ho = *(unsigned int*)o;
    if (OUTF){
        float* fo = fout + (size_t)d * DOUT + lane * CPL;
        if (CPL == 4){ float4 q = {f[0], f[1], f[2], f[3]}; *(float4*)fo = q; }
        else { float2 q = {f[0], f[1]}; *(float2*)fo = q; }
    }
}

// 128x128-tile LDS-staged bf16 MFMA GEMM, BK=64, double-buffered, 8 waves.
// T4 counted-vmcnt schedule: stage issues 4 vmem/thread; per K-step wait
// vmcnt(4) (previous stage only) + raw s_barrier, so the new stage's loads
// stay in flight across the barrier. Padded LDS C-tile coalesced epilogue.
template<int KTOT, int DIN, int NYT, bool HAS_S, bool RELUCTX>
__global__ __launch_bounds__(512, 4) void gemm128(
        const unsigned short* __restrict__ hA,
        const unsigned short* __restrict__ S,
        const unsigned short* __restrict__ WT,
        const float* __restrict__ ctxb,
        const int* __restrict__ yb,
        unsigned short* __restrict__ outb,
        int outstride, int ctxstride){
    __shared__ unsigned short lds[2][2][128 * 64];
    constexpr int NT = KTOT / 64;
    constexpr int CSTR = 136;                // padded C-tile row stride (elems)
    int tid = threadIdx.x;
    int wid = tid >> 6, lane = tid & 63;
    int l15 = lane & 15, lk = lane >> 4;
    int wr = wid >> 2, wc = wid & 3;

    int nwg = gridDim.x;
    int orig = blockIdx.x;
    int q = nwg >> 3, r8 = nwg & 7;
    int xcd = orig & 7, pos = orig >> 3;
    int wg = (xcd < r8 ? xcd * (q + 1) : r8 * (q + 1) + (xcd - r8) * q) + pos;
    int mrow0 = (wg / NYT) * 128;
    int ncol0 = (wg % NYT) * 128;

    f32x4 acc[4][2];
#pragma unroll
    for (int m = 0; m < 4; ++m)
#pragma unroll
        for (int n = 0; n < 2; ++n) acc[m][n] = (f32x4){0.f, 0.f, 0.f, 0.f};

    auto stage = [&](int kt, int buf){
#pragma unroll
        for (int i = 0; i < 2; ++i){
            int idx = i * 512 + tid;
            int r = idx >> 3;
            int cbl = idx & 7;
            int cb = cbl ^ (r & 7);
            int k0 = kt * 64 + cb * 8;
            int gr = mrow0 + r; if (gr > NN - 1) gr = NN - 1;
            const unsigned short* ga;
            if (HAS_S && kt >= DIN / 64) ga = S + (size_t)gr * (4 * DIN) + (k0 - DIN);
            else                         ga = hA + (size_t)gr * DIN + k0;
            GLDS16(ga, &lds[buf][0][(size_t)(i * 8 + wid) * 512]);
            int gj = ncol0 + r;
            const unsigned short* gb = WT + (size_t)gj * KTOT + k0;
            GLDS16(gb, &lds[buf][1][(size_t)(i * 8 + wid) * 512]);
        }
    };

    stage(0, 0);
    int buf = 0;
#pragma unroll 1
    for (int kt = 0; kt < NT; ++kt){
        if (kt + 1 < NT){
            stage(kt + 1, buf ^ 1);
            asm volatile("s_waitcnt vmcnt(4)" ::: "memory");
        } else {
            asm volatile("s_waitcnt vmcnt(0)" ::: "memory");
        }
        __builtin_amdgcn_s_barrier();
        __builtin_amdgcn_sched_barrier(0);
#pragma unroll
        for (int ks = 0; ks < 2; ++ks){
            int c = ks * 4 + lk;
            bf16x8 a[4], b[2];
#pragma unroll
            for (int m = 0; m < 4; ++m){
                int r = wr * 64 + m * 16 + l15;
                a[m] = *(const bf16x8*)&lds[buf][0][r * 64 + (c ^ (r & 7)) * 8];
            }
#pragma unroll
            for (int n = 0; n < 2; ++n){
                int j = wc * 32 + n * 16 + l15;
                b[n] = *(const bf16x8*)&lds[buf][1][j * 64 + (c ^ (j & 7)) * 8];
            }
#pragma unroll
            for (int m = 0; m < 4; ++m)
#pragma unroll
                for (int n = 0; n < 2; ++n)
                    acc[m][n] = __builtin_amdgcn_mfma_f32_16x16x32_bf16(b[n], a[m], acc[m][n], 0, 0, 0);
        }
        __builtin_amdgcn_sched_barrier(0);
        __builtin_amdgcn_s_barrier();
        buf ^= 1;
    }

    // epilogue: fragments -> padded LDS C-tile -> contiguous 256B-row stores
    unsigned short* ldsC = &lds[0][0][0];   // 128 x 136 elems = 34.8 KB
#pragma unroll
    for (int m = 0; m < 4; ++m){
        int rl = wr * 64 + m * 16 + l15;
        int row = mrow0 + rl;
        const float* cb = RELUCTX ? (ctxb + (size_t)yb[row < NN ? row : NN - 1] * ctxstride) : ctxb;
#pragma unroll
        for (int n = 0; n < 2; ++n){
            int g = wc * 8 + n * 4 + lk;     // granule (4 elems) 0..31
            unsigned short o[4];
#pragma unroll
            for (int r = 0; r < 4; ++r){
                float v = acc[m][n][r] + cb[ncol0 + g * 4 + r];
                if (RELUCTX) v = fmaxf(v, 0.f);
                o[r] = f2bf(v);
            }
            *(uint2*)&ldsC[rl * CSTR + g * 4] = *(uint2*)o;
        }
    }
    __syncthreads();
#pragma unroll
    for (int i = 0; i < 4; ++i){
        int idx = i * 512 + tid;             // 128 rows x 16 chunks(8 elems)
        int rl = idx >> 4;
        int c = idx & 15;
        bf16x8 v = *(const bf16x8*)&ldsC[rl * CSTR + c * 8];
        int row = mrow0 + rl;
        if (row < NN)
            *(bf16x8*)(outb + (size_t)row * outstride + ncol0 + c * 8) = v;
    }
}

// Fused y_pred = log_softmax(ybf @ WTz^T + lzb)
__global__ __launch_bounds__(512, 2) void logit_lsm_kernel(
        const unsigned short* __restrict__ ybf,
        const unsigned short* __restrict__ WTz,
        const float* __restrict__ lzb,
        float* __restrict__ ypred){
    __shared__ unsigned short ldsB[2][VV * 32];
    __shared__ float lzbs[VV];
    __shared__ float pm[4][16][2], ps[4][16][2];
    int tid = threadIdx.x;
    int wid = tid >> 6, lane = tid & 63;
    int l15 = lane & 15, lk = lane >> 4;
    int wr = wid >> 1, wc = wid & 1;
    int row = blockIdx.x * 64 + wr * 16 + l15;

    lzbs[tid] = lzb[tid];

    bf16x8 aR[4];
    const unsigned short* ap = ybf + (size_t)row * EMB;
#pragma unroll
    for (int kt = 0; kt < 4; ++kt) aR[kt] = *(const bf16x8*)(ap + kt * 32 + lk * 8);

    auto stageB = [&](int kt, int buf){
#pragma unroll
        for (int i = 0; i < 4; ++i){
            int idx = i * 512 + tid;
            int j = idx >> 2;
            int cbl = idx & 3;
            int cb = cbl ^ (j & 3);
            const unsigned short* gb = WTz + (size_t)j * EMB + kt * 32 + cb * 8;
            GLDS16(gb, &ldsB[buf][(size_t)(i * 8 + wid) * 512]);
        }
    };

    f32x4 acc[16];
#pragma unroll
    for (int n = 0; n < 16; ++n) acc[n] = (f32x4){0.f, 0.f, 0.f, 0.f};

    stageB(0, 0);
    __syncthreads();
    int buf = 0;
#pragma unroll
    for (int kt = 0; kt < 4; ++kt){
        if (kt < 3) stageB(kt + 1, buf ^ 1);
#pragma unroll
        for (int nh = 0; nh < 2; ++nh){
            bf16x8 b[8];
#pragma unroll
            for (int n8 = 0; n8 < 8; ++n8){
                int j = wc * 256 + (nh * 8 + n8) * 16 + l15;
                b[n8] = *(const bf16x8*)&ldsB[buf][j * 32 + ((lk ^ (j & 3)) * 8)];
            }
#pragma unroll
            for (int n8 = 0; n8 < 8; ++n8)
                acc[nh * 8 + n8] = __builtin_amdgcn_mfma_f32_16x16x32_bf16(b[n8], aR[kt], acc[nh * 8 + n8], 0, 0, 0);
        }
        __syncthreads();
        buf ^= 1;
    }

    float m = -3.0e38f;
#pragma unroll
    for (int n = 0; n < 16; ++n){
        int colb = wc * 256 + n * 16 + lk * 4;
#pragma unroll
        for (int r = 0; r < 4; ++r){
            float v = acc[n][r] + lzbs[colb + r];
            acc[n][r] = v;
            m = fmaxf(m, v);
        }
    }
    m = fmaxf(m, __shfl_xor(m, 16));
    m = fmaxf(m, __shfl_xor(m, 32));
    float s = 0.f;
#pragma unroll
    for (int n = 0; n < 16; ++n)
#pragma unroll
        for (int r = 0; r < 4; ++r) s += expf(acc[n][r] - m);
    s += __shfl_xor(s, 16);
    s += __shfl_xor(s, 32);
    if (lk == 0){ pm[wr][l15][wc] = m; ps[wr][l15][wc] = s; }
    __syncthreads();
    float m0 = pm[wr][l15][0], m1 = pm[wr][l15][1];
    float s0 = ps[wr][l15][0], s1 = ps[wr][l15][1];
    float M = fmaxf(m0, m1);
    float l = M + logf(expf(m0 - M) * s0 + expf(m1 - M) * s1);

    float* orow = ypred + (size_t)row * VV + wc * 256;
#pragma unroll
    for (int n = 0; n < 16; ++n){
        int colb = n * 16 + lk * 4;
        float4 q = {acc[n][0] - l, acc[n][1] - l, acc[n][2] - l, acc[n][3] - l};
        *(float4*)(orow + colb) = q;
    }
}

// ---- edge head, factored ----
__global__ __launch_bounds__(256) void zpair_kernel(const float* __restrict__ y,
        const float* __restrict__ Wg, float* __restrict__ z){
    __shared__ float ylds[16][132];
    __shared__ float wg[2 * EMB * NSRT];
    for (int i = threadIdx.x; i < 2 * EMB * NSRT; i += 256) wg[i] = Wg[i];
    int n0 = blockIdx.x * 16;
    for (int i = threadIdx.x; i < 16 * 32; i += 256){
        int node = i >> 5, f4 = i & 31;
        *(float4*)&ylds[node][f4 * 4] = *(const float4*)(y + (size_t)(n0 + node) * EMB + f4 * 4);
    }
    __syncthreads();
    int t = threadIdx.x;
    if (t < 160){
        int node = t & 15, c = t >> 4;
        int base = (c >= 5) ? EMB : 0;
        int cc = (c >= 5) ? c - 5 : c;
        float acc = 0.f;
#pragma unroll 4
        for (int k = 0; k < EMB; ++k) acc += ylds[node][k] * wg[(base + k) * NSRT + cc];
        z[(size_t)(n0 + node) * 10 + c] = acc;
    }
}

__global__ __launch_bounds__(256) void edge2_kernel(const int* __restrict__ src,
        const int* __restrict__ dst, const float* __restrict__ z,
        const float* __restrict__ bg, float* __restrict__ out){
    int e = blockIdx.x * 256 + threadIdx.x; if (e >= EE) return;
    int s = src[e], d = dst[e];
    const float* zs = z + (size_t)s * 10;
    const float* zd = z + (size_t)d * 10 + 5;
    float l0 = zs[0] + zd[0] + bg[0];
    float l1 = zs[1] + zd[1] + bg[1];
    float l2 = zs[2] + zd[2] + bg[2];
    float l3 = zs[3] + zd[3] + bg[3];
    float l4 = zs[4] + zd[4] + bg[4];
    float m = fmaxf(fmaxf(fmaxf(l0, l1), fmaxf(l2, l3)), l4);
    float ssum = expf(l0 - m) + expf(l1 - m) + expf(l2 - m) + expf(l3 - m) + expf(l4 - m);
    float lg = m + logf(ssum);
    float* o = out + (size_t)e * NSRT;
    o[0] = l0 - lg; o[1] = l1 - lg; o[2] = l2 - lg; o[3] = l3 - lg; o[4] = l4 - lg;
}

__global__ __launch_bounds__(256) void i2f_kernel(const int* __restrict__ in,
        float* __restrict__ out, int n){
    int i = blockIdx.x * 256 + threadIdx.x;
    if (i < n) out[i] = (float)in[i];
}

extern "C" void kernel_launch(void* const* d_in, const int* in_sizes, int n_in,
                              void* d_out, int out_size, void* d_ws, size_t ws_size,
                              hipStream_t stream){
    const float* x    = (const float*)d_in[0];
    const int*   xb   = (const int*)d_in[1];
    const int*   ty   = (const int*)d_in[2];
    const int*   ei   = (const int*)d_in[3];
    const int*   et   = (const int*)d_in[4];
    const int*   tyb  = (const int*)d_in[5];
    const float* emb  = (const float*)d_in[6];
    const float* Ws1 = (const float*)d_in[7],  *Wr1 = (const float*)d_in[8];
    const float* Wc1 = (const float*)d_in[9],  *b1  = (const float*)d_in[10];
    const float* Ws2 = (const float*)d_in[11], *Wr2 = (const float*)d_in[12];
    const float* Wc2 = (const float*)d_in[13], *b2  = (const float*)d_in[14];
    const float* Ws3 = (const float*)d_in[15], *Wr3 = (const float*)d_in[16];
    const float* Wc3 = (const float*)d_in[17], *b3  = (const float*)d_in[18];
    const float* lzw = (const float*)d_in[19], *lzb = (const float*)d_in[20];
    const float* lgw = (const float*)d_in[21], *lgb = (const float*)d_in[22];

    const int* src = ei;
    const int* dst = ei + EE;

    float* out = (float*)d_out;
    const size_t OFF_Y  = 0;
    const size_t OFF_EI = (size_t)NN * EMB;
    const size_t OFF_ET = OFF_EI + 2 * (size_t)EE;
    const size_t OFF_YP = OFF_ET + (size_t)EE;
    const size_t OFF_EP = OFF_YP + (size_t)NN * VV;

    char* w = (char*)d_ws;
    auto alloc = [&](size_t bytes){ char* p = w; w += (bytes + 255) & ~(size_t)255; return p; };
    unsigned short* h0  = (unsigned short*)alloc((size_t)NN * EMB * 2);
    unsigned short* h1  = (unsigned short*)alloc((size_t)NN * HH * 2);
    unsigned short* h2  = (unsigned short*)alloc((size_t)NN * HH * 2);
    unsigned short* ybf = (unsigned short*)alloc((size_t)NN * EMB * 2);
    unsigned short* G2  = (unsigned short*)alloc((size_t)NN * 5 * HH * 2);
    unsigned short* G3  = (unsigned short*)alloc((size_t)NN * 5 * EMB * 2);
    unsigned short* WT1 = (unsigned short*)alloc((size_t)HH * (5 * EMB) * 2);
    unsigned short* WT2p= (unsigned short*)alloc((size_t)(5 * HH) * HH * 2);
    unsigned short* WT3p= (unsigned short*)alloc((size_t)(5 * EMB) * HH * 2);
    unsigned short* WTz = (unsigned short*)alloc((size_t)VV * EMB * 2);
    float* ctxs  = (float*)alloc(BB * F_IN * 4);
    float* ctx   = (float*)alloc(BB * F_IN * 4);
    float* ctxb1 = (float*)alloc(BB * HH * 4);
    float* ctxb2 = (float*)alloc(BB * HH * 4);
    float* ctxb3 = (float*)alloc(BB * EMB * 4);
    float* zpair = (float*)alloc((size_t)NN * 10 * 4);
    float* zerob = (float*)alloc((size_t)5 * HH * 4);
    int* deg    = (int*)alloc((size_t)NN * 4);
    int* rowptr = (int*)alloc(((size_t)NN + 1) * 4);
    int* cursor = (int*)alloc((size_t)NN * 4);
    int* eidx   = (int*)alloc((size_t)EE * 4);
    int* bsum   = (int*)alloc((size_t)SNB * 4);
    int* boff   = (int*)alloc((size_t)SNB * 4);

    // y_pred region of d_out doubles as S scratch (layer 1 only) until logit_lsm
    unsigned short* Sbuf = (unsigned short*)(out + OFF_YP);

    // CSR by dst
    hipMemsetAsync(deg, 0, (size_t)NN * 4, stream);
    hipMemsetAsync(zerob, 0, (size_t)5 * HH * 4, stream);
    hist_kernel<<<(EE + 255) / 256, 256, 0, stream>>>(dst, deg);
    scanA_kernel<<<SNB, 256, 0, stream>>>(deg, bsum);
    scanB_kernel<<<1, 256, 0, stream>>>(bsum, boff);
    scanC_kernel<<<SNB, 256, 0, stream>>>(deg, boff, rowptr, cursor);
    fill_kernel<<<(EE + 255) / 256, 256, 0, stream>>>(src, dst, et, cursor, eidx);

    // ctx + folded ctx@Wc+b tables
    hipMemsetAsync(ctxs, 0, BB * F_IN * 4, stream);
    ctxsum_kernel<<<(MM + CTX_RPB - 1) / CTX_RPB, 256, 0, stream>>>(x, xb, ctxs);
    ctxdiv_kernel<<<BB, 256, 0, stream>>>(ctxs, xb, ctx);
    ctxb_kernel<<<dim3(BB, HH / 64), 64, 0, stream>>>(ctx, Wc1, b1, ctxb1, HH);
    ctxb_kernel<<<dim3(BB, HH / 64), 64, 0, stream>>>(ctx, Wc2, b2, ctxb2, HH);
    ctxb_kernel<<<dim3(BB, EMB / 64), 64, 0, stream>>>(ctx, Wc3, b3, ctxb3, EMB);

    // weight stacks
    build_wt<<<(HH * 5 * EMB + 255) / 256, 256, 0, stream>>>(Ws1, Wr1, WT1, EMB, HH, 5 * EMB);
    build_wtp<<<(5 * HH * HH + 255) / 256, 256, 0, stream>>>(Ws2, Wr2, WT2p, HH, HH);
    build_wtp<<<(5 * EMB * HH + 255) / 256, 256, 0, stream>>>(Ws3, Wr3, WT3p, HH, EMB);
    build_wt<<<(VV * EMB + 255) / 256, 256, 0, stream>>>(lzw, lzw, WTz, EMB, VV, EMB);

    // h0 = embeds[tgt_y].sum(1)
    embed_kernel<<<NN * EMB / 256, 256, 0, stream>>>(ty, emb, h0);

    const int MT = (NN + 127) / 128;  // 1563

    // layer 1: aggregate in din-space then fat GEMM (KTOT=640)
    sbuild_kernel<EMB><<<NN / 4, 256, 0, stream>>>(h0, rowptr, eidx, Sbuf);
    gemm128<640, 128, 2, true, true><<<MT * 2, 512, 0, stream>>>(
        h0, Sbuf, WT1, ctxb1, tyb, h1, HH, HH);

    // layer 2: project-first -> aggregate in dout-space
    gemm128<256, 256, 10, false, false><<<MT * 10, 512, 0, stream>>>(
        h1, nullptr, WT2p, zerob, nullptr, G2, 5 * HH, 0);
    agg_kernel<HH, false><<<NN / 4, 256, 0, stream>>>(
        G2, rowptr, eidx, ctxb2, tyb, h2, nullptr);

    // layer 3: project-first -> aggregate, dual f32+bf16 out
    gemm128<256, 256, 5, false, false><<<MT * 5, 512, 0, stream>>>(
        h2, nullptr, WT3p, zerob, nullptr, G3, 5 * EMB, 0);
    agg_kernel<EMB, true><<<NN / 4, 256, 0, stream>>>(
        G3, rowptr, eidx, ctxb3, tyb, ybf, out + OFF_Y);

    // edge head tables
    zpair_kernel<<<NN / 16, 256, 0, stream>>>(out + OFF_Y, lgw, zpair);

    // y_pred = log_softmax(y @ lin_z_w + lin_z_b), fused
    logit_lsm_kernel<<<NN / 64, 512, 0, stream>>>(ybf, WTz, lzb, out + OFF_YP);

    // per-edge head
    edge2_kernel<<<(EE + 255) / 256, 256, 0, stream>>>(src, dst, zpair, lgb, out + OFF_EP);
    i2f_kernel<<<(2 * EE + 255) / 256, 256, 0, stream>>>(ei, out + OFF_EI, 2 * EE);
    i2f_kernel<<<(EE + 255) / 256, 256, 0, stream>>>(et, out + OFF_ET, EE);
}

// Round 16
// 1243.657 us; speedup vs baseline: 1.1692x; 1.1155x over previous
//
#include <hip/hip_runtime.h>
#include <hip/hip_bf16.h>
#include <stdint.h>

#define NN 200000
#define MM 100000
#define EE 600000
#define BB 64
#define F_IN 256
#define HH 256
#define EMB 128
#define VV 512
#define NSRT 5

typedef __attribute__((ext_vector_type(8))) short bf16x8;
typedef __attribute__((ext_vector_type(4))) float f32x4;

__device__ __forceinline__ unsigned short f2bf(float x){
    union { float f; unsigned int u; } c; c.f = x;
    unsigned int r = c.u + 0x7FFFu + ((c.u >> 16) & 1u);
    return (unsigned short)(r >> 16);
}
__device__ __forceinline__ float bf2f(unsigned short b){
    union { unsigned int u; float f; } c; c.u = ((unsigned int)b) << 16;
    return c.f;
}

__device__ __forceinline__ int lowerb(const int* a, int n, int key){
    int lo = 0, hi = n;
    while (lo < hi){ int mid = (lo + hi) >> 1; if (a[mid] < key) lo = mid + 1; else hi = mid; }
    return lo;
}

#define GLDS16(g, l) __builtin_amdgcn_global_load_lds( \
    (const __attribute__((address_space(1))) unsigned int*)(g), \
    (__attribute__((address_space(3))) unsigned int*)(l), 16, 0, 0)

#define CTX_RPB 128
#define SNB ((NN + 1023) / 1024)

// ---- segment boundaries for pre1 (blocks of 256 threads) ----
#define NB_HIST  ((EE + 255) / 256)                    // 2344
#define NB_CTXS  ((MM + CTX_RPB - 1) / CTX_RPB)        // 782
#define NB_WT1   ((HH * 5 * EMB) / 256)                // 640
#define NB_WT2P  ((5 * HH * HH) / 256)                 // 1280
#define NB_WT3P  ((5 * EMB * HH) / 256)                // 640
#define NB_WTZ   ((VV * EMB) / 256)                    // 256
#define NB_EMBED (NN * EMB / 256)                      // 100000
#define NB_I2FEI ((2 * EE + 255) / 256)                // 4688
#define NB_I2FET ((EE + 255) / 256)                    // 2344
#define NB_PRE1  (NB_HIST + NB_CTXS + NB_WT1 + NB_WT2P + NB_WT3P + NB_WTZ + NB_EMBED + NB_I2FEI + NB_I2FET)

__device__ __forceinline__ void wt_body(const float* Ws, const float* Wr,
        unsigned short* WT, int din, int dout, int ktot, int b, int t){
    size_t idx = (size_t)b * 256 + t;
    int j = (int)(idx / ktot), k = (int)(idx % ktot);
    float v = (k < din) ? Ws[(size_t)k * dout + j] : Wr[(size_t)(k - din) * dout + j];
    WT[idx] = f2bf(v);
}

// wtp: jj = blk*dout + j: blk 0 -> Ws[k][j], blk 1+r -> Wr[r][k][j]
__device__ __forceinline__ void wtp_body(const float* Ws, const float* Wr,
        unsigned short* WT, int K, int dout, int b, int t){
    size_t idx = (size_t)b * 256 + t;
    int jj = (int)(idx / K), k = (int)(idx % K);
    int blk = jj / dout, j = jj % dout;
    float v = (blk == 0) ? Ws[(size_t)k * dout + j]
                         : Wr[((size_t)(blk - 1) * K + k) * dout + j];
    WT[idx] = f2bf(v);
}

// pre1: hist | ctxsum | wt1 | wt2p | wt3p | wtz | embed | i2f(ei) | i2f(et)
__global__ __launch_bounds__(256) void pre1_kernel(
        const int* __restrict__ dst, int* __restrict__ deg,
        const float* __restrict__ x, const int* __restrict__ xb, float* __restrict__ ctxs,
        const float* __restrict__ Ws1, const float* __restrict__ Wr1, unsigned short* __restrict__ WT1,
        const float* __restrict__ Ws2, const float* __restrict__ Wr2, unsigned short* __restrict__ WT2p,
        const float* __restrict__ Ws3, const float* __restrict__ Wr3, unsigned short* __restrict__ WT3p,
        const float* __restrict__ lzw, unsigned short* __restrict__ WTz,
        const int* __restrict__ ty, const float* __restrict__ emb, unsigned short* __restrict__ h0,
        const int* __restrict__ ei, const int* __restrict__ et,
        float* __restrict__ outEI, float* __restrict__ outET){
    int b = blockIdx.x, t = threadIdx.x;
    if (b < NB_HIST){
        int e = b * 256 + t;
        if (e < EE) atomicAdd(&deg[dst[e]], 1);
        return;
    }
    b -= NB_HIST;
    if (b < NB_CTXS){
        int r0 = b * CTX_RPB;
        int r1 = r0 + CTX_RPB; if (r1 > MM) r1 = MM;
        float s = 0.f;
        int g = xb[r0];
        for (int r = r0; r < r1; ++r){
            int gb = xb[r];
            if (gb != g){ atomicAdd(&ctxs[g * F_IN + t], s); s = 0.f; g = gb; }
            s += x[(size_t)r * F_IN + t];
        }
        atomicAdd(&ctxs[g * F_IN + t], s);
        return;
    }
    b -= NB_CTXS;
    if (b < NB_WT1){ wt_body(Ws1, Wr1, WT1, EMB, HH, 5 * EMB, b, t); return; }
    b -= NB_WT1;
    if (b < NB_WT2P){ wtp_body(Ws2, Wr2, WT2p, HH, HH, b, t); return; }
    b -= NB_WT2P;
    if (b < NB_WT3P){ wtp_body(Ws3, Wr3, WT3p, HH, EMB, b, t); return; }
    b -= NB_WT3P;
    if (b < NB_WTZ){ wt_body(lzw, lzw, WTz, EMB, VV, EMB, b, t); return; }
    b -= NB_WTZ;
    if (b < NB_EMBED){
        size_t idx = (size_t)b * 256 + t;
        int i = (int)(idx >> 7), c = (int)(idx & 127);
        int t0 = ty[i * 3], t1 = ty[i * 3 + 1], t2 = ty[i * 3 + 2];
        float v = emb[(size_t)t0 * EMB + c] + emb[(size_t)t1 * EMB + c] + emb[(size_t)t2 * EMB + c];
        h0[idx] = f2bf(v);
        return;
    }
    b -= NB_EMBED;
    if (b < NB_I2FEI){
        int i = b * 256 + t;
        if (i < 2 * EE) outEI[i] = (float)ei[i];
        return;
    }
    b -= NB_I2FEI;
    {
        int i = b * 256 + t;
        if (i < EE) outET[i] = (float)et[i];
    }
}

// pre2: scanA (196 blocks) | ctxdiv (64 blocks)
__global__ __launch_bounds__(256) void pre2_kernel(const int* __restrict__ deg,
        int* __restrict__ bsum, const float* __restrict__ ctxs,
        const int* __restrict__ xb, float* __restrict__ ctx){
    int b = blockIdx.x, tid = threadIdx.x;
    if (b < SNB){
        __shared__ int wsum[4];
        int wid = tid >> 6, lane = tid & 63;
        int base = b * 1024 + tid * 4;
        int s = 0;
        if (base + 3 < NN){ int4 v = *(const int4*)(deg + base); s = v.x + v.y + v.z + v.w; }
        else { for (int i = 0; i < 4; ++i){ int idx = base + i; if (idx < NN) s += deg[idx]; } }
#pragma unroll
        for (int off = 1; off < 64; off <<= 1) s += __shfl_xor(s, off);
        if (lane == 0) wsum[wid] = s;
        __syncthreads();
        if (tid == 0) bsum[b] = wsum[0] + wsum[1] + wsum[2] + wsum[3];
        return;
    }
    int g = b - SNB;
    int lo = lowerb(xb, MM, g), hi = lowerb(xb, MM, g + 1);
    int c = hi - lo; if (c < 1) c = 1;
    ctx[g * F_IN + tid] = ctxs[g * F_IN + tid] / (float)c;
}

__device__ __forceinline__ void ctxb_body(const float* ctx, const float* Wc,
        const float* bvec, float* out, int dout, int b, int t){
    int idx = b * 256 + t;
    int g = idx / dout, j = idx % dout;
    float acc = bvec[j];
    const float* cr = ctx + g * F_IN;
    for (int k = 0; k < F_IN; ++k) acc += cr[k] * Wc[(size_t)k * dout + j];
    out[(size_t)g * dout + j] = acc;
}

// pre3: scanB (1 block) | ctxb1 (64) | ctxb2 (64) | ctxb3 (32)
__global__ __launch_bounds__(256) void pre3_kernel(const int* __restrict__ bsum,
        int* __restrict__ boff, const float* __restrict__ ctx,
        const float* __restrict__ Wc1, const float* __restrict__ b1, float* __restrict__ ctxb1,
        const float* __restrict__ Wc2, const float* __restrict__ b2, float* __restrict__ ctxb2,
        const float* __restrict__ Wc3, const float* __restrict__ b3, float* __restrict__ ctxb3){
    int b = blockIdx.x, t = threadIdx.x;
    if (b == 0){
        __shared__ int lds[256];
        int v = (t < SNB) ? bsum[t] : 0;
        lds[t] = v; __syncthreads();
        for (int off = 1; off < 256; off <<= 1){
            int n = (t >= off) ? lds[t - off] : 0;
            __syncthreads();
            lds[t] += n;
            __syncthreads();
        }
        if (t < SNB) boff[t] = lds[t] - v;
        return;
    }
    b -= 1;
    if (b < 64){ ctxb_body(ctx, Wc1, b1, ctxb1, HH, b, t); return; }
    b -= 64;
    if (b < 64){ ctxb_body(ctx, Wc2, b2, ctxb2, HH, b, t); return; }
    b -= 64;
    ctxb_body(ctx, Wc3, b3, ctxb3, EMB, b, t);
}

__global__ __launch_bounds__(256) void scanC_kernel(const int* __restrict__ deg,
        const int* __restrict__ boff, int* __restrict__ rowptr, int* __restrict__ cursor){
    __shared__ int wsum[4];
    int tid = threadIdx.x, wid = tid >> 6, lane = tid & 63;
    int base = blockIdx.x * 1024 + tid * 4;
    int d0 = 0, d1 = 0, d2 = 0, d3 = 0;
    if (base + 3 < NN){ int4 v = *(const int4*)(deg + base); d0 = v.x; d1 = v.y; d2 = v.z; d3 = v.w; }
    else if (base < NN){
        d0 = deg[base];
        if (base + 1 < NN) d1 = deg[base + 1];
        if (base + 2 < NN) d2 = deg[base + 2];
    }
    int tsum = d0 + d1 + d2 + d3;
    int run = tsum;
#pragma unroll
    for (int off = 1; off < 64; off <<= 1){
        int n = __shfl_up(run, off);
        if (lane >= off) run += n;
    }
    if (lane == 63) wsum[wid] = run;
    int texcl = run - tsum;
    __syncthreads();
    int woff = 0;
    for (int i = 0; i < wid; ++i) woff += wsum[i];
    int p = boff[blockIdx.x] + woff + texcl;
    if (base < NN){
        rowptr[base] = p; cursor[base] = p; p += d0;
        if (base + 1 < NN){ rowptr[base + 1] = p; cursor[base + 1] = p; p += d1; }
        if (base + 2 < NN){ rowptr[base + 2] = p; cursor[base + 2] = p; p += d2; }
        if (base + 3 < NN){ rowptr[base + 3] = p; cursor[base + 3] = p; p += d3; }
    }
    if (blockIdx.x == 0 && tid == 0) rowptr[NN] = EE;
}

__global__ __launch_bounds__(256) void fill_kernel(const int* __restrict__ src,
        const int* __restrict__ dst, const int* __restrict__ et,
        int* __restrict__ cursor, int* __restrict__ eidx){
    int e = blockIdx.x * 256 + threadIdx.x; if (e >= EE) return;
    int p = atomicAdd(&cursor[dst[e]], 1);
    eidx[p] = src[e] | (et[e] << 28);
}

// S[d][r][:] = sum of h[src] over incoming edges of type r
template<int DIN>
__global__ __launch_bounds__(256) void sbuild_kernel(const unsigned short* __restrict__ h,
        const int* __restrict__ rowptr, const int* __restrict__ eidx,
        unsigned short* __restrict__ S){
    constexpr int CPL = DIN / 64;
    int wid = threadIdx.x >> 6, lane = threadIdx.x & 63;
    int d = blockIdx.x * 4 + wid;
    int lo = rowptr[d], hi = rowptr[d + 1];
    float acc0[CPL], acc1[CPL], acc2[CPL], acc3[CPL];
#pragma unroll
    for (int c = 0; c < CPL; ++c){ acc0[c] = 0.f; acc1[c] = 0.f; acc2[c] = 0.f; acc3[c] = 0.f; }
    const unsigned short* hl = h + lane * CPL;
    int e = lo;
    for (; e + 1 < hi; e += 2){
        int pkA = eidx[e], pkB = eidx[e + 1];
        int sA = pkA & 0x0FFFFFFF, rA = pkA >> 28;
        int sB = pkB & 0x0FFFFFFF, rB = pkB >> 28;
        unsigned short vA[CPL], vB[CPL];
        if (CPL == 4){
            *(uint2*)vA = *(const uint2*)(hl + (size_t)sA * DIN);
            *(uint2*)vB = *(const uint2*)(hl + (size_t)sB * DIN);
        } else {
            *(unsigned int*)vA = *(const unsigned int*)(hl + (size_t)sA * DIN);
            *(unsigned int*)vB = *(const unsigned int*)(hl + (size_t)sB * DIN);
        }
        float a0 = (rA == 0) ? 1.f : 0.f, a1 = (rA == 1) ? 1.f : 0.f;
        float a2 = (rA == 2) ? 1.f : 0.f, a3 = (rA == 3) ? 1.f : 0.f;
        float b0 = (rB == 0) ? 1.f : 0.f, b1 = (rB == 1) ? 1.f : 0.f;
        float b2 = (rB == 2) ? 1.f : 0.f, b3 = (rB == 3) ? 1.f : 0.f;
#pragma unroll
        for (int c = 0; c < CPL; ++c){
            float fA = bf2f(vA[c]), fB = bf2f(vB[c]);
            acc0[c] += a0 * fA + b0 * fB;
            acc1[c] += a1 * fA + b1 * fB;
            acc2[c] += a2 * fA + b2 * fB;
            acc3[c] += a3 * fA + b3 * fB;
        }
    }
    if (e < hi){
        int pk = eidx[e];
        int s = pk & 0x0FFFFFFF, r = pk >> 28;
        unsigned short v[CPL];
        if (CPL == 4) *(uint2*)v = *(const uint2*)(hl + (size_t)s * DIN);
        else          *(unsigned int*)v = *(const unsigned int*)(hl + (size_t)s * DIN);
        float m0 = (r == 0) ? 1.f : 0.f, m1 = (r == 1) ? 1.f : 0.f;
        float m2 = (r == 2) ? 1.f : 0.f, m3 = (r == 3) ? 1.f : 0.f;
#pragma unroll
        for (int c = 0; c < CPL; ++c){
            float f = bf2f(v[c]);
            acc0[c] += m0 * f; acc1[c] += m1 * f; acc2[c] += m2 * f; acc3[c] += m3 * f;
        }
    }
    unsigned short* So = S + (size_t)d * 4 * DIN + lane * CPL;
    unsigned short o[CPL];
#pragma unroll
    for (int c = 0; c < CPL; ++c) o[c] = f2bf(acc0[c]);
    if (CPL == 4) *(uint2*)(So) = *(uint2*)o; else *(unsigned int*)(So) = *(unsigned int*)o;
#pragma unroll
    for (int c = 0; c < CPL; ++c) o[c] = f2bf(acc1[c]);
    if (CPL == 4) *(uint2*)(So + DIN) = *(uint2*)o; else *(unsigned int*)(So + DIN) = *(unsigned int*)o;
#pragma unroll
    for (int c = 0; c < CPL; ++c) o[c] = f2bf(acc2[c]);
    if (CPL == 4) *(uint2*)(So + 2 * DIN) = *(uint2*)o; else *(unsigned int*)(So + 2 * DIN) = *(unsigned int*)o;
#pragma unroll
    for (int c = 0; c < CPL; ++c) o[c] = f2bf(acc3[c]);
    if (CPL == 4) *(uint2*)(So + 3 * DIN) = *(uint2*)o; else *(unsigned int*)(So + 3 * DIN) = *(unsigned int*)o;
}

// out[d] = relu(G[d][self] + sum_{e->d} G[src_e][(1+r)*DOUT] + ctxb[yb[d]])
template<int DOUT, bool OUTF>
__global__ __launch_bounds__(256) void agg_kernel(const unsigned short* __restrict__ G,
        const int* __restrict__ rowptr, const int* __restrict__ eidx,
        const float* __restrict__ ctxb, const int* __restrict__ yb,
        unsigned short* __restrict__ hout, float* __restrict__ fout){
    constexpr int CPL = DOUT / 64;
    constexpr int STR = 5 * DOUT;
    int wid = threadIdx.x >> 6, lane = threadIdx.x & 63;
    int d = blockIdx.x * 4 + wid;
    int lo = rowptr[d], hi = rowptr[d + 1];
    int g = yb[d];
    const unsigned short* Gl = G + lane * CPL;
    float acc[CPL];
    {
        unsigned short sv[CPL];
        if (CPL == 4) *(uint2*)sv = *(const uint2*)(Gl + (size_t)d * STR);
        else          *(unsigned int*)sv = *(const unsigned int*)(Gl + (size_t)d * STR);
#pragma unroll
        for (int c = 0; c < CPL; ++c) acc[c] = bf2f(sv[c]);
    }
    int e = lo;
    for (; e + 1 < hi; e += 2){
        int pkA = eidx[e], pkB = eidx[e + 1];
        int sA = pkA & 0x0FFFFFFF, rA = pkA >> 28;
        int sB = pkB & 0x0FFFFFFF, rB = pkB >> 28;
        const unsigned short* ga = Gl + (size_t)sA * STR + (1 + rA) * DOUT;
        const unsigned short* gb = Gl + (size_t)sB * STR + (1 + rB) * DOUT;
        unsigned short vA[CPL], vB[CPL];
        if (CPL == 4){ *(uint2*)vA = *(const uint2*)ga; *(uint2*)vB = *(const uint2*)gb; }
        else { *(unsigned int*)vA = *(const unsigned int*)ga; *(unsigned int*)vB = *(const unsigned int*)gb; }
#pragma unroll
        for (int c = 0; c < CPL; ++c) acc[c] += bf2f(vA[c]) + bf2f(vB[c]);
    }
    if (e < hi){
        int pk = eidx[e];
        int s = pk & 0x0FFFFFFF, r = pk >> 28;
        const unsigned short* ga = Gl + (size_t)s * STR + (1 + r) * DOUT;
        unsigned short v[CPL];
        if (CPL == 4) *(uint2*)v = *(const uint2*)ga;
        else          *(unsigned int*)v = *(const unsigned int*)ga;
#pragma unroll
        for (int c = 0; c < CPL; ++c) acc[c] += bf2f(v[c]);
    }
    const float* cb = ctxb + (size_t)g * DOUT + lane * CPL;
    float f[CPL];
    unsigned short o[CPL];
#pragma unroll
    for (int c = 0; c < CPL; ++c){ f[c] = fmaxf(acc[c] + cb[c], 0.f); o[c] = f2bf(f[c]); }
    unsigned short* ho = hout + (size_t)d * DOUT + lane * CPL;
    if (CPL == 4) *(uint2*)ho = *(uint2*)o; else *(unsigned int*)ho = *(unsigned int*)o;
    if (OUTF){
        float* fo = fout + (size_t)d * DOUT + lane * CPL;
        if (CPL == 4){ float4 q = {f[0], f[1], f[2], f[3]}; *(float4*)fo = q; }
        else { float2 q = {f[0], f[1]}; *(float2*)fo = q; }
    }
}

// 128x128-tile LDS-staged bf16 MFMA GEMM, BK=64, double-buffered, 8 waves.
// Counted-vmcnt schedule + padded LDS C-tile coalesced epilogue.
template<int KTOT, int DIN, int NYT, bool HAS_S, bool RELUCTX>
__global__ __launch_bounds__(512, 4) void gemm128(
        const unsigned short* __restrict__ hA,
        const unsigned short* __restrict__ S,
        const unsigned short* __restrict__ WT,
        const float* __restrict__ ctxb,
        const int* __restrict__ yb,
        unsigned short* __restrict__ outb,
        int outstride, int ctxstride){
    __shared__ unsigned short lds[2][2][128 * 64];
    constexpr int NT = KTOT / 64;
    constexpr int CSTR = 136;
    int tid = threadIdx.x;
    int wid = tid >> 6, lane = tid & 63;
    int l15 = lane & 15, lk = lane >> 4;
    int wr = wid >> 2, wc = wid & 3;

    int nwg = gridDim.x;
    int orig = blockIdx.x;
    int q = nwg >> 3, r8 = nwg & 7;
    int xcd = orig & 7, pos = orig >> 3;
    int wg = (xcd < r8 ? xcd * (q + 1) : r8 * (q + 1) + (xcd - r8) * q) + pos;
    int mrow0 = (wg / NYT) * 128;
    int ncol0 = (wg % NYT) * 128;

    f32x4 acc[4][2];
#pragma unroll
    for (int m = 0; m < 4; ++m)
#pragma unroll
        for (int n = 0; n < 2; ++n) acc[m][n] = (f32x4){0.f, 0.f, 0.f, 0.f};

    auto stage = [&](int kt, int buf){
#pragma unroll
        for (int i = 0; i < 2; ++i){
            int idx = i * 512 + tid;
            int r = idx >> 3;
            int cbl = idx & 7;
            int cb = cbl ^ (r & 7);
            int k0 = kt * 64 + cb * 8;
            int gr = mrow0 + r; if (gr > NN - 1) gr = NN - 1;
            const unsigned short* ga;
            if (HAS_S && kt >= DIN / 64) ga = S + (size_t)gr * (4 * DIN) + (k0 - DIN);
            else                         ga = hA + (size_t)gr * DIN + k0;
            GLDS16(ga, &lds[buf][0][(size_t)(i * 8 + wid) * 512]);
            int gj = ncol0 + r;
            const unsigned short* gb = WT + (size_t)gj * KTOT + k0;
            GLDS16(gb, &lds[buf][1][(size_t)(i * 8 + wid) * 512]);
        }
    };

    stage(0, 0);
    int buf = 0;
#pragma unroll 1
    for (int kt = 0; kt < NT; ++kt){
        if (kt + 1 < NT){
            stage(kt + 1, buf ^ 1);
            asm volatile("s_waitcnt vmcnt(4)" ::: "memory");
        } else {
            asm volatile("s_waitcnt vmcnt(0)" ::: "memory");
        }
        __builtin_amdgcn_s_barrier();
        __builtin_amdgcn_sched_barrier(0);
#pragma unroll
        for (int ks = 0; ks < 2; ++ks){
            int c = ks * 4 + lk;
            bf16x8 a[4], b[2];
#pragma unroll
            for (int m = 0; m < 4; ++m){
                int r = wr * 64 + m * 16 + l15;
                a[m] = *(const bf16x8*)&lds[buf][0][r * 64 + (c ^ (r & 7)) * 8];
            }
#pragma unroll
            for (int n = 0; n < 2; ++n){
                int j = wc * 32 + n * 16 + l15;
                b[n] = *(const bf16x8*)&lds[buf][1][j * 64 + (c ^ (j & 7)) * 8];
            }
#pragma unroll
            for (int m = 0; m < 4; ++m)
#pragma unroll
                for (int n = 0; n < 2; ++n)
                    acc[m][n] = __builtin_amdgcn_mfma_f32_16x16x32_bf16(b[n], a[m], acc[m][n], 0, 0, 0);
        }
        __builtin_amdgcn_sched_barrier(0);
        __builtin_amdgcn_s_barrier();
        buf ^= 1;
    }

    unsigned short* ldsC = &lds[0][0][0];
#pragma unroll
    for (int m = 0; m < 4; ++m){
        int rl = wr * 64 + m * 16 + l15;
        int row = mrow0 + rl;
        const float* cb = RELUCTX ? (ctxb + (size_t)yb[row < NN ? row : NN - 1] * ctxstride) : ctxb;
#pragma unroll
        for (int n = 0; n < 2; ++n){
            int g = wc * 8 + n * 4 + lk;
            unsigned short o[4];
#pragma unroll
            for (int r = 0; r < 4; ++r){
                float v = acc[m][n][r] + cb[ncol0 + g * 4 + r];
                if (RELUCTX) v = fmaxf(v, 0.f);
                o[r] = f2bf(v);
            }
            *(uint2*)&ldsC[rl * CSTR + g * 4] = *(uint2*)o;
        }
    }
    __syncthreads();
#pragma unroll
    for (int i = 0; i < 4; ++i){
        int idx = i * 512 + tid;
        int rl = idx >> 4;
        int c = idx & 15;
        bf16x8 v = *(const bf16x8*)&ldsC[rl * CSTR + c * 8];
        int row = mrow0 + rl;
        if (row < NN)
            *(bf16x8*)(outb + (size_t)row * outstride + ncol0 + c * 8) = v;
    }
}

// Fused y_pred = log_softmax(ybf @ WTz^T + lzb)
__global__ __launch_bounds__(512, 2) void logit_lsm_kernel(
        const unsigned short* __restrict__ ybf,
        const unsigned short* __restrict__ WTz,
        const float* __restrict__ lzb,
        float* __restrict__ ypred){
    __shared__ unsigned short ldsB[2][VV * 32];
    __shared__ float lzbs[VV];
    __shared__ float pm[4][16][2], ps[4][16][2];
    int tid = threadIdx.x;
    int wid = tid >> 6, lane = tid & 63;
    int l15 = lane & 15, lk = lane >> 4;
    int wr = wid >> 1, wc = wid & 1;
    int row = blockIdx.x * 64 + wr * 16 + l15;

    lzbs[tid] = lzb[tid];

    bf16x8 aR[4];
    const unsigned short* ap = ybf + (size_t)row * EMB;
#pragma unroll
    for (int kt = 0; kt < 4; ++kt) aR[kt] = *(const bf16x8*)(ap + kt * 32 + lk * 8);

    auto stageB = [&](int kt, int buf){
#pragma unroll
        for (int i = 0; i < 4; ++i){
            int idx = i * 512 + tid;
            int j = idx >> 2;
            int cbl = idx & 3;
            int cb = cbl ^ (j & 3);
            const unsigned short* gb = WTz + (size_t)j * EMB + kt * 32 + cb * 8;
            GLDS16(gb, &ldsB[buf][(size_t)(i * 8 + wid) * 512]);
        }
    };

    f32x4 acc[16];
#pragma unroll
    for (int n = 0; n < 16; ++n) acc[n] = (f32x4){0.f, 0.f, 0.f, 0.f};

    stageB(0, 0);
    __syncthreads();
    int buf = 0;
#pragma unroll
    for (int kt = 0; kt < 4; ++kt){
        if (kt < 3) stageB(kt + 1, buf ^ 1);
#pragma unroll
        for (int nh = 0; nh < 2; ++nh){
            bf16x8 b[8];
#pragma unroll
            for (int n8 = 0; n8 < 8; ++n8){
                int j = wc * 256 + (nh * 8 + n8) * 16 + l15;
                b[n8] = *(const bf16x8*)&ldsB[buf][j * 32 + ((lk ^ (j & 3)) * 8)];
            }
#pragma unroll
            for (int n8 = 0; n8 < 8; ++n8)
                acc[nh * 8 + n8] = __builtin_amdgcn_mfma_f32_16x16x32_bf16(b[n8], aR[kt], acc[nh * 8 + n8], 0, 0, 0);
        }
        __syncthreads();
        buf ^= 1;
    }

    float m = -3.0e38f;
#pragma unroll
    for (int n = 0; n < 16; ++n){
        int colb = wc * 256 + n * 16 + lk * 4;
#pragma unroll
        for (int r = 0; r < 4; ++r){
            float v = acc[n][r] + lzbs[colb + r];
            acc[n][r] = v;
            m = fmaxf(m, v);
        }
    }
    m = fmaxf(m, __shfl_xor(m, 16));
    m = fmaxf(m, __shfl_xor(m, 32));
    float s = 0.f;
#pragma unroll
    for (int n = 0; n < 16; ++n)
#pragma unroll
        for (int r = 0; r < 4; ++r) s += expf(acc[n][r] - m);
    s += __shfl_xor(s, 16);
    s += __shfl_xor(s, 32);
    if (lk == 0){ pm[wr][l15][wc] = m; ps[wr][l15][wc] = s; }
    __syncthreads();
    float m0 = pm[wr][l15][0], m1 = pm[wr][l15][1];
    float s0 = ps[wr][l15][0], s1 = ps[wr][l15][1];
    float M = fmaxf(m0, m1);
    float l = M + logf(expf(m0 - M) * s0 + expf(m1 - M) * s1);

    float* orow = ypred + (size_t)row * VV + wc * 256;
#pragma unroll
    for (int n = 0; n < 16; ++n){
        int colb = n * 16 + lk * 4;
        float4 q = {acc[n][0] - l, acc[n][1] - l, acc[n][2] - l, acc[n][3] - l};
        *(float4*)(orow + colb) = q;
    }
}

// ---- edge head, factored ----
__global__ __launch_bounds__(256) void zpair_kernel(const float* __restrict__ y,
        const float* __restrict__ Wg, float* __restrict__ z){
    __shared__ float ylds[16][132];
    __shared__ float wg[2 * EMB * NSRT];
    for (int i = threadIdx.x; i < 2 * EMB * NSRT; i += 256) wg[i] = Wg[i];
    int n0 = blockIdx.x * 16;
    for (int i = threadIdx.x; i < 16 * 32; i += 256){
        int node = i >> 5, f4 = i & 31;
        *(float4*)&ylds[node][f4 * 4] = *(const float4*)(y + (size_t)(n0 + node) * EMB + f4 * 4);
    }
    __syncthreads();
    int t = threadIdx.x;
    if (t < 160){
        int node = t & 15, c = t >> 4;
        int base = (c >= 5) ? EMB : 0;
        int cc = (c >= 5) ? c - 5 : c;
        float acc = 0.f;
#pragma unroll 4
        for (int k = 0; k < EMB; ++k) acc += ylds[node][k] * wg[(base + k) * NSRT + cc];
        z[(size_t)(n0 + node) * 10 + c] = acc;
    }
}

__global__ __launch_bounds__(256) void edge2_kernel(const int* __restrict__ src,
        const int* __restrict__ dst, const float* __restrict__ z,
        const float* __restrict__ bg, float* __restrict__ out){
    int e = blockIdx.x * 256 + threadIdx.x; if (e >= EE) return;
    int s = src[e], d = dst[e];
    const float* zs = z + (size_t)s * 10;
    const float* zd = z + (size_t)d * 10 + 5;
    float l0 = zs[0] + zd[0] + bg[0];
    float l1 = zs[1] + zd[1] + bg[1];
    float l2 = zs[2] + zd[2] + bg[2];
    float l3 = zs[3] + zd[3] + bg[3];
    float l4 = zs[4] + zd[4] + bg[4];
    float m = fmaxf(fmaxf(fmaxf(l0, l1), fmaxf(l2, l3)), l4);
    float ssum = expf(l0 - m) + expf(l1 - m) + expf(l2 - m) + expf(l3 - m) + expf(l4 - m);
    float lg = m + logf(ssum);
    float* o = out + (size_t)e * NSRT;
    o[0] = l0 - lg; o[1] = l1 - lg; o[2] = l2 - lg; o[3] = l3 - lg; o[4] = l4 - lg;
}

extern "C" void kernel_launch(void* const* d_in, const int* in_sizes, int n_in,
                              void* d_out, int out_size, void* d_ws, size_t ws_size,
                              hipStream_t stream){
    const float* x    = (const float*)d_in[0];
    const int*   xb   = (const int*)d_in[1];
    const int*   ty   = (const int*)d_in[2];
    const int*   ei   = (const int*)d_in[3];
    const int*   et   = (const int*)d_in[4];
    const int*   tyb  = (const int*)d_in[5];
    const float* emb  = (const float*)d_in[6];
    const float* Ws1 = (const float*)d_in[7],  *Wr1 = (const float*)d_in[8];
    const float* Wc1 = (const float*)d_in[9],  *b1  = (const float*)d_in[10];
    const float* Ws2 = (const float*)d_in[11], *Wr2 = (const float*)d_in[12];
    const float* Wc2 = (const float*)d_in[13], *b2  = (const float*)d_in[14];
    const float* Ws3 = (const float*)d_in[15], *Wr3 = (const float*)d_in[16];
    const float* Wc3 = (const float*)d_in[17], *b3  = (const float*)d_in[18];
    const float* lzw = (const float*)d_in[19], *lzb = (const float*)d_in[20];
    const float* lgw = (const float*)d_in[21], *lgb = (const float*)d_in[22];

    const int* src = ei;
    const int* dst = ei + EE;

    float* out = (float*)d_out;
    const size_t OFF_Y  = 0;
    const size_t OFF_EI = (size_t)NN * EMB;
    const size_t OFF_ET = OFF_EI + 2 * (size_t)EE;
    const size_t OFF_YP = OFF_ET + (size_t)EE;
    const size_t OFF_EP = OFF_YP + (size_t)NN * VV;

    char* w = (char*)d_ws;
    auto alloc = [&](size_t bytes){ char* p = w; w += (bytes + 255) & ~(size_t)255; return p; };
    unsigned short* h0  = (unsigned short*)alloc((size_t)NN * EMB * 2);
    unsigned short* h1  = (unsigned short*)alloc((size_t)NN * HH * 2);
    unsigned short* h2  = (unsigned short*)alloc((size_t)NN * HH * 2);
    unsigned short* ybf = (unsigned short*)alloc((size_t)NN * EMB * 2);
    unsigned short* G2  = (unsigned short*)alloc((size_t)NN * 5 * HH * 2);
    unsigned short* G3  = (unsigned short*)alloc((size_t)NN * 5 * EMB * 2);
    unsigned short* WT1 = (unsigned short*)alloc((size_t)HH * (5 * EMB) * 2);
    unsigned short* WT2p= (unsigned short*)alloc((size_t)(5 * HH) * HH * 2);
    unsigned short* WT3p= (unsigned short*)alloc((size_t)(5 * EMB) * HH * 2);
    unsigned short* WTz = (unsigned short*)alloc((size_t)VV * EMB * 2);
    float* ctxs  = (float*)alloc(BB * F_IN * 4);
    float* ctx   = (float*)alloc(BB * F_IN * 4);
    float* ctxb1 = (float*)alloc(BB * HH * 4);
    float* ctxb2 = (float*)alloc(BB * HH * 4);
    float* ctxb3 = (float*)alloc(BB * EMB * 4);
    float* zpair = (float*)alloc((size_t)NN * 10 * 4);
    float* zerob = (float*)alloc((size_t)5 * HH * 4);
    int* deg    = (int*)alloc((size_t)NN * 4);
    int* rowptr = (int*)alloc(((size_t)NN + 1) * 4);
    int* cursor = (int*)alloc((size_t)NN * 4);
    int* eidx   = (int*)alloc((size_t)EE * 4);
    int* bsum   = (int*)alloc((size_t)SNB * 4);
    int* boff   = (int*)alloc((size_t)SNB * 4);

    // y_pred region of d_out doubles as S scratch (layer 1 only) until logit_lsm
    unsigned short* Sbuf = (unsigned short*)(out + OFF_YP);

    hipMemsetAsync(deg, 0, (size_t)NN * 4, stream);
    hipMemsetAsync(zerob, 0, (size_t)5 * HH * 4, stream);
    hipMemsetAsync(ctxs, 0, BB * F_IN * 4, stream);

    // fused preprocessing: hist | ctxsum | weight stacks | embed | i2f x2
    pre1_kernel<<<NB_PRE1, 256, 0, stream>>>(
        dst, deg, x, xb, ctxs,
        Ws1, Wr1, WT1, Ws2, Wr2, WT2p, Ws3, Wr3, WT3p, lzw, WTz,
        ty, emb, h0, ei, et, out + OFF_EI, out + OFF_ET);
    pre2_kernel<<<SNB + BB, 256, 0, stream>>>(deg, bsum, ctxs, xb, ctx);
    pre3_kernel<<<1 + 64 + 64 + 32, 256, 0, stream>>>(bsum, boff, ctx,
        Wc1, b1, ctxb1, Wc2, b2, ctxb2, Wc3, b3, ctxb3);
    scanC_kernel<<<SNB, 256, 0, stream>>>(deg, boff, rowptr, cursor);
    fill_kernel<<<(EE + 255) / 256, 256, 0, stream>>>(src, dst, et, cursor, eidx);

    const int MT = (NN + 127) / 128;  // 1563

    // layer 1: aggregate in din-space then fat GEMM (KTOT=640)
    sbuild_kernel<EMB><<<NN / 4, 256, 0, stream>>>(h0, rowptr, eidx, Sbuf);
    gemm128<640, 128, 2, true, true><<<MT * 2, 512, 0, stream>>>(
        h0, Sbuf, WT1, ctxb1, tyb, h1, HH, HH);

    // layer 2: project-first -> aggregate in dout-space
    gemm128<256, 256, 10, false, false><<<MT * 10, 512, 0, stream>>>(
        h1, nullptr, WT2p, zerob, nullptr, G2, 5 * HH, 0);
    agg_kernel<HH, false><<<NN / 4, 256, 0, stream>>>(
        G2, rowptr, eidx, ctxb2, tyb, h2, nullptr);

    // layer 3: project-first -> aggregate, dual f32+bf16 out
    gemm128<256, 256, 5, false, false><<<MT * 5, 512, 0, stream>>>(
        h2, nullptr, WT3p, zerob, nullptr, G3, 5 * EMB, 0);
    agg_kernel<EMB, true><<<NN / 4, 256, 0, stream>>>(
        G3, rowptr, eidx, ctxb3, tyb, ybf, out + OFF_Y);

    // edge head tables
    zpair_kernel<<<NN / 16, 256, 0, stream>>>(out + OFF_Y, lgw, zpair);

    // y_pred = log_softmax(y @ lin_z_w + lin_z_b), fused
    logit_lsm_kernel<<<NN / 64, 512, 0, stream>>>(ybf, WTz, lzb, out + OFF_YP);

    // per-edge head
    edge2_kernel<<<(EE + 255) / 256, 256, 0, stream>>>(src, dst, zpair, lgb, out + OFF_EP);
}